// Round 7
// baseline (465.807 us; speedup 1.0000x reference)
//
#include <hip/hip_runtime.h>
#include <math.h>

#define G_    64
#define N_    512
#define H_    64
#define NT_   32768
#define ET_   1048576
#define EPG_  16384      // edges per graph
#define KP_   359
#define NP2_  22976
#define FIN_  128

// ---------------- prep: BkT transpose (blocks 0..95) + PT tables (blocks 96..101) ----
// BkT[c][d*64+h] = Bk[c][h*64+d];  PT[c][i][h] = sum_d Bk_c[h,d]*basis_i[d],
// basis 0..2 = posW rows, basis 3 = posb
__global__ void k_prep(const float* __restrict__ Bk, const float* __restrict__ posW,
                       const float* __restrict__ posb,
                       float* __restrict__ BkT, float* __restrict__ PT) {
    int b = blockIdx.x, t = threadIdx.x;
    if (b < 96) {
        int idx = b * 256 + t;
        int c = idx >> 12, r = idx & 4095;
        int h = r >> 6, d = r & 63;
        BkT[c * 4096 + d * 64 + h] = Bk[c * 4096 + h * 64 + d];
    } else {
        int c = b - 96;
        int i = t >> 6, h = t & 63;
        const float* B = Bk + c * 4096 + h * 64;
        float acc = 0.f;
        for (int d = 0; d < 64; d++) {
            float vd = (i < 3) ? posW[i*64 + d] : posb[d];
            acc += B[d] * vd;
        }
        PT[c*256 + i*64 + h] = acc;
    }
}

// ---------------- col-CSR build: hist + scan + scatter, one block/graph, LDS cursors
__global__ __launch_bounds__(1024)
void k_buildc(const int* __restrict__ row, const int* __restrict__ col,
              int* __restrict__ colptr, int* __restrict__ colcsr,
              float* __restrict__ deg, int* __restrict__ nmap) {
    __shared__ int hc[N_];
    int g = blockIdx.x, t = threadIdx.x;
    int nbase = g * N_, ebase = g * EPG_;
    if (t < N_) { hc[t] = 0; nmap[nbase + t] = -1; }
    __syncthreads();
    for (int i = t; i < EPG_; i += 1024)
        atomicAdd(&hc[col[ebase + i] & (N_ - 1)], 1);
    __syncthreads();
    if (t < N_) deg[nbase + t] = (float)hc[t];
    __syncthreads();
    if (t < 64) {                       // one wave: exclusive scan of 512 entries
        int base8 = t * 8;
        int loc[8];
        int tot = 0;
        #pragma unroll
        for (int i = 0; i < 8; i++) { int v = hc[base8 + i]; loc[i] = tot; tot += v; }
        int pref = tot;
        for (int off = 1; off < 64; off <<= 1) {
            int u = __shfl_up(pref, off);
            if ((t & 63) >= off) pref += u;
        }
        pref -= tot;                    // exclusive
        #pragma unroll
        for (int i = 0; i < 8; i++) hc[base8 + i] = pref + loc[i];
    }
    __syncthreads();
    if (t < N_) colptr[nbase + t] = ebase + hc[t];
    if (g == 0 && t == 0) colptr[NT_] = ET_;
    __syncthreads();
    for (int i = t; i < EPG_; i += 1024) {
        int cg = col[ebase + i], rg = row[ebase + i];
        int pc = atomicAdd(&hc[cg & (N_ - 1)], 1);
        colcsr[ebase + pc] = rg;        // L2-local: one graph's 64 KB region per block
    }
}

// ---------------- stage-1 node sums via LDS scatter: nsum[n] = (Σw*cx,Σw*cy,Σw*cz,Σw)
__global__ __launch_bounds__(1024)
void k_nsum1s(const int* __restrict__ row, const int* __restrict__ col,
              const float* __restrict__ ea, const float* __restrict__ coords,
              float4* __restrict__ nsum) {
    __shared__ float tile[N_ * 4];      // 8 KB
    int g = blockIdx.x, t = threadIdx.x;
    int nbase = g * N_, ebase = g * EPG_;
    for (int i = t; i < N_ * 4; i += 1024) tile[i] = 0.f;
    __syncthreads();
    for (int i = t; i < EPG_; i += 1024) {
        int rg = row[ebase + i] & (N_ - 1);
        int cg = col[ebase + i];
        float w = ea[ebase + i];
        atomicAdd(&tile[rg*4 + 0], w * coords[cg*3 + 0]);
        atomicAdd(&tile[rg*4 + 1], w * coords[cg*3 + 1]);
        atomicAdd(&tile[rg*4 + 2], w * coords[cg*3 + 2]);
        atomicAdd(&tile[rg*4 + 3], w);
    }
    __syncthreads();
    float* out = (float*)&nsum[nbase];
    for (int i = t; i < N_ * 4; i += 1024) out[i] = tile[i];
}

// ---------------- stage-2 masked node sums + deg2 via LDS scatter ----------------
__global__ __launch_bounds__(1024)
void k_s2pres(const int* __restrict__ row, const int* __restrict__ col,
              const int* __restrict__ nmap, const float* __restrict__ coords,
              float4* __restrict__ nsum2, float* __restrict__ deg2) {
    __shared__ float tile[KP_ * 4];     // 5.6 KB
    __shared__ float dg[KP_];
    int g = blockIdx.x, t = threadIdx.x;
    int pbase = g * KP_, ebase = g * EPG_;
    for (int i = t; i < KP_ * 4; i += 1024) tile[i] = 0.f;
    if (t < KP_) dg[t] = 0.f;
    __syncthreads();
    for (int i = t; i < EPG_; i += 1024) {
        int rg = row[ebase + i], cg = col[ebase + i];
        int mr = nmap[rg], mc = nmap[cg];
        if ((mr | mc) >= 0) {           // both >= 0
            int lr = mr - pbase;
            atomicAdd(&tile[lr*4 + 0], coords[cg*3 + 0]);
            atomicAdd(&tile[lr*4 + 1], coords[cg*3 + 1]);
            atomicAdd(&tile[lr*4 + 2], coords[cg*3 + 2]);
            atomicAdd(&tile[lr*4 + 3], 1.f);
            atomicAdd(&dg[mc - pbase], 1.f);
        }
    }
    __syncthreads();
    float* out = (float*)&nsum2[pbase];
    for (int i = t; i < KP_ * 4; i += 1024) out[i] = tile[i];
    if (t < KP_) deg2[pbase + t] = dg[t];
}

// ---------------- dual GEMM: outA = in@Wa (rows optionally scattered), outB = in@Wb + bias
__global__ __launch_bounds__(256)
void k_gemm_dual(const float* __restrict__ in, int K,
                 const float* __restrict__ Wa, const float* __restrict__ Wb,
                 const float* __restrict__ bias, const int* __restrict__ permA,
                 float* __restrict__ outA, float* __restrict__ outB) {
    __shared__ float inT[32 * FIN_];
    int row0 = blockIdx.x * 32;
    int t = threadIdx.x;
    for (int idx = t; idx < 32 * K; idx += 256) inT[idx] = in[row0 * K + idx];
    __syncthreads();
    int c = t & 63, rb = t >> 6;            // wave rb handles rows rb*8 .. rb*8+7
    const float* ip = inT + (rb * 8) * K;
    float aA[8] = {0,0,0,0,0,0,0,0};
    float aB[8] = {0,0,0,0,0,0,0,0};
    for (int k = 0; k < K; k += 4) {
        float wa0 = Wa[(k+0)*64 + c], wa1 = Wa[(k+1)*64 + c];
        float wa2 = Wa[(k+2)*64 + c], wa3 = Wa[(k+3)*64 + c];
        float wb0 = Wb[(k+0)*64 + c], wb1 = Wb[(k+1)*64 + c];
        float wb2 = Wb[(k+2)*64 + c], wb3 = Wb[(k+3)*64 + c];
        #pragma unroll
        for (int r = 0; r < 8; r++) {
            float4 xv = *(const float4*)&ip[r*K + k];
            aA[r] += xv.x*wa0; aB[r] += xv.x*wb0;
            aA[r] += xv.y*wa1; aB[r] += xv.y*wb1;
            aA[r] += xv.z*wa2; aB[r] += xv.z*wb2;
            aA[r] += xv.w*wa3; aB[r] += xv.w*wb3;
        }
    }
    float bv = bias[c];
    #pragma unroll
    for (int r = 0; r < 8; r++) {
        int node = row0 + rb*8 + r;
        int rowA = permA ? permA[node] : node;
        outA[rowA*64 + c] = aA[r];
        outB[node*64 + c] = aB[r] + bv;
    }
}

// ---------------- stage-1 agg gather ----------------
__global__ __launch_bounds__(256)
void k_gagg(const int* __restrict__ colptr, const int* __restrict__ ccsr,
            const float* __restrict__ y, float* __restrict__ agg) {
    int node = blockIdx.x * 4 + (threadIdx.x >> 6);
    int lane = threadIdx.x & 63;
    int start = colptr[node], end = colptr[node + 1];
    float acc = 0.f;
    #pragma unroll 8
    for (int k = start; k < end; k++) {
        int r = ccsr[k];
        acc += y[r*64 + lane];
    }
    agg[node*64 + lane] = acc;
}

// ---------------- graph_norm stats: one-pass sum & sumsq partials ----------------
__global__ __launch_bounds__(256)
void k_gnstat(const float* __restrict__ hs, const float* __restrict__ agg,
              const float* __restrict__ deg, float* __restrict__ partial,
              int NPG, int CH, int npc) {
    __shared__ float r1[256], r2[256];
    int b = blockIdx.x;
    int g = b / CH, chunk = b % CH;
    int t = threadIdx.x, c = t & 63, grp = t >> 6;
    int n0 = chunk * npc;
    int nend = min(n0 + npc, NPG);
    float s1 = 0.f, s2 = 0.f;
    for (int n = n0 + grp; n < nend; n += 4) {
        int node = g * NPG + n;
        float v = hs[node*64 + c] + agg[node*64 + c] / fmaxf(deg[node], 1.f);
        s1 += v; s2 += v * v;
    }
    r1[t] = s1; r2[t] = s2;
    __syncthreads();
    if (grp == 0) {
        partial[b*128 + c]      = r1[c] + r1[64+c] + r1[128+c] + r1[192+c];
        partial[b*128 + 64 + c] = r2[c] + r2[64+c] + r2[128+c] + r2[192+c];
    }
}

// ---------------- graph_norm finalize ----------------
__global__ void k_gnfin(const float* __restrict__ partial, const float* __restrict__ ms,
                        int CH, int NPG,
                        float* __restrict__ mval, float* __restrict__ istdv) {
    int g = blockIdx.x, t = threadIdx.x;   // 64 threads
    float s1 = 0.f, s2 = 0.f;
    for (int i = 0; i < CH; i++) {
        s1 += partial[(g*CH + i)*128 + t];
        s2 += partial[(g*CH + i)*128 + 64 + t];
    }
    float m = s1 / (float)NPG, q = s2 / (float)NPG, msv = ms[t];
    float var = q - msv * m * m * (2.f - msv);   // E[(h-ms*m)^2]
    mval[g*64 + t]  = msv * m;
    istdv[g*64 + t] = rsqrtf(var + 1e-5f);
}

// ---------------- stage-1 fused: gn-apply + elu + delta(from nsum) + propagate ----------------
__global__ __launch_bounds__(256)
void k_gnprop(const float* __restrict__ hself, const float* __restrict__ agg,
              const float* __restrict__ deg,
              const float* __restrict__ mval, const float* __restrict__ istdv,
              const float* __restrict__ w, const float* __restrict__ b,
              const float4* __restrict__ nsum, const int* __restrict__ cls,
              const float* __restrict__ PT, const float* __restrict__ BkT,
              float* __restrict__ out) {
    __shared__ float hT[256];
    int t = threadIdx.x;
    int node = blockIdx.x * 4 + (t >> 6);
    int lane = t & 63;
    int g = node >> 9;
    float4 s4 = nsum[node];
    int c = cls[node];
    const float* P = PT + c * 256;
    float d = s4.x*P[lane] + s4.y*P[64+lane] + s4.z*P[128+lane] + s4.w*P[192+lane];
    float v = hself[node*64 + lane] + agg[node*64 + lane] / fmaxf(deg[node], 1.f);
    v = w[lane] * (v - mval[g*64 + lane]) * istdv[g*64 + lane] + b[lane];
    v = v > 0.f ? v : expm1f(v);
    v += d;
    hT[t] = v;
    __syncthreads();
    float ssum = v;
    #pragma unroll
    for (int off = 32; off; off >>= 1) ssum += __shfl_xor(ssum, off);
    const float* B  = BkT + c * 4096;
    const float* hv = hT + (t & ~63);
    float acc = 0.f;
    #pragma unroll 8
    for (int j = 0; j < 64; j++) acc += B[j*64 + lane] * hv[j];
    out[node*64 + lane] = acc + d * ssum;
}

// ---------------- top-k per graph (desc score, ties by lower idx) ----------------
__global__ void k_topk(const float* __restrict__ hp, const float* __restrict__ p,
                       const int* __restrict__ cls,
                       int* __restrict__ perm, float* __restrict__ tanhv,
                       int* __restrict__ node_map, int* __restrict__ class2) {
    __shared__ float key[N_];
    __shared__ int   idxS[N_];
    __shared__ float pS[64];
    __shared__ float nrm;
    int g = blockIdx.x, t = threadIdx.x;
    if (t < 64) pS[t] = p[t];
    __syncthreads();
    if (t == 0) {
        float s = 0.f;
        for (int i = 0; i < 64; i++) s += pS[i] * pS[i];
        nrm = sqrtf(s);
    }
    __syncthreads();
    {
        float acc = 0.f;
        const float* hv = hp + (size_t)(g*N_ + t) * 64;
        for (int cdx = 0; cdx < 64; cdx++) acc += hv[cdx] * pS[cdx];
        key[t]  = acc / nrm;
        idxS[t] = t;
    }
    __syncthreads();
    for (int k = 2; k <= N_; k <<= 1) {
        for (int j = k >> 1; j > 0; j >>= 1) {
            int i = t, ixj = i ^ j;
            if (ixj > i) {
                float ki = key[i], kj = key[ixj];
                int   ii = idxS[i], ij = idxS[ixj];
                bool before = (ki > kj) || (ki == kj && ii < ij);
                bool dir = ((i & k) == 0);
                if (dir ? !before : before) {
                    key[i] = kj; key[ixj] = ki;
                    idxS[i] = ij; idxS[ixj] = ii;
                }
            }
            __syncthreads();
        }
    }
    if (t < KP_) {
        int orig  = idxS[t];
        int gnode = g * N_ + orig;
        int pj    = g * KP_ + t;
        perm[pj]     = gnode;
        tanhv[pj]    = tanhf(key[t]);
        node_map[gnode] = pj;
        class2[pj]   = cls[gnode];
    }
}

// ---------------- stage-2 fused: gather*tanh + delta2(from nsum2) + propagate ----------------
__global__ __launch_bounds__(256)
void k_prop2v(const float* __restrict__ hp, const int* __restrict__ perm,
              const float* __restrict__ tanhv,
              const float4* __restrict__ nsum2, const int* __restrict__ cls2,
              const float* __restrict__ PT, const float* __restrict__ BkT,
              float* __restrict__ out) {
    __shared__ float hT[256];
    int t = threadIdx.x;
    int j = blockIdx.x * 4 + (t >> 6);
    int lane = t & 63;
    int orig = perm[j];
    float tv = tanhv[j];
    float4 s4 = nsum2[j];
    int c = cls2[j];
    const float* P = PT + c * 256;
    float d = s4.x*P[lane] + s4.y*P[64+lane] + s4.z*P[128+lane] + s4.w*P[192+lane];
    float v = hp[orig*64 + lane] * tv + d;
    hT[t] = v;
    __syncthreads();
    float ssum = v;
    #pragma unroll
    for (int off = 32; off; off >>= 1) ssum += __shfl_xor(ssum, off);
    const float* B  = BkT + c * 4096;
    const float* hv = hT + (t & ~63);
    float acc = 0.f;
    #pragma unroll 8
    for (int jj = 0; jj < 64; jj++) acc += B[jj*64 + lane] * hv[jj];
    out[j*64 + lane] = acc + d * ssum;
}

// ---------------- stage-2 agg gather (zero-expanded y2full, single indirection) ----------------
__global__ __launch_bounds__(256)
void k_gagg2(const int* __restrict__ colptr, const int* __restrict__ ccsr,
             const int* __restrict__ perm, const float* __restrict__ y2full,
             float* __restrict__ agg2) {
    int j = blockIdx.x * 4 + (threadIdx.x >> 6);
    int lane = threadIdx.x & 63;
    int orig = perm[j];
    int start = colptr[orig], end = colptr[orig + 1];
    float acc = 0.f;
    #pragma unroll 8
    for (int k = start; k < end; k++) {
        int r = ccsr[k];
        acc += y2full[r*64 + lane];
    }
    agg2[j*64 + lane] = acc;
}

// ---------------- fused stage-2 gn-apply + elu + readout partials ----------------
__global__ __launch_bounds__(256)
void k_gnrd(const float* __restrict__ hs, const float* __restrict__ agg,
            const float* __restrict__ deg2,
            const float* __restrict__ mval, const float* __restrict__ istdv,
            const float* __restrict__ w, const float* __restrict__ b,
            float* __restrict__ part, int CH, int npc) {
    __shared__ float r1[256], r2[256];
    int blk = blockIdx.x;
    int g = blk / CH, chunk = blk % CH;
    int t = threadIdx.x, c = t & 63, grp = t >> 6;
    int n0 = chunk * npc, nend = min(n0 + npc, KP_);
    float mv = mval[g*64 + c], is = istdv[g*64 + c], wv = w[c], bv = b[c];
    float s = 0.f, m = -1e30f;
    for (int n = n0 + grp; n < nend; n += 4) {
        int node = g * KP_ + n;
        float v = hs[node*64 + c] + agg[node*64 + c] / fmaxf(deg2[node], 1.f);
        v = wv * (v - mv) * is + bv;
        v = v > 0.f ? v : expm1f(v);
        s += v; m = fmaxf(m, v);
    }
    r1[t] = s; r2[t] = m;
    __syncthreads();
    if (grp == 0) {
        part[blk*128 + c]      = r1[c] + r1[64+c] + r1[128+c] + r1[192+c];
        part[blk*128 + 64 + c] = fmaxf(fmaxf(r2[c], r2[64+c]), fmaxf(r2[128+c], r2[192+c]));
    }
}

// ---------------- readout finalize: lin1 relu -> lin2 -> log_softmax ----------------
__global__ void k_rfin(const float* __restrict__ part, int CH,
                       const float* __restrict__ l1W, const float* __restrict__ l1b,
                       const float* __restrict__ l2W, const float* __restrict__ l2b,
                       float* __restrict__ out) {
    __shared__ float gv[192], rS[64];
    int g = blockIdx.x, t = threadIdx.x;   // 64 threads
    float s = 0.f, m = -1e30f;
    for (int i = 0; i < CH; i++) {
        s += part[(g*CH + i)*128 + t];
        m = fmaxf(m, part[(g*CH + i)*128 + 64 + t]);
    }
    gv[t] = s / (float)KP_;
    gv[64 + t] = m;
    gv[128 + t] = s;
    __syncthreads();
    float acc = l1b[t];
    for (int k = 0; k < 192; k++) acc += gv[k] * l1W[k*64 + t];
    rS[t] = fmaxf(acc, 0.f);
    __syncthreads();
    if (t == 0) {
        float l0 = l2b[0], l1v = l2b[1];
        for (int hh = 0; hh < 64; hh++) { l0 += rS[hh]*l2W[hh*2+0]; l1v += rS[hh]*l2W[hh*2+1]; }
        float mx  = fmaxf(l0, l1v);
        float lse = mx + logf(expf(l0 - mx) + expf(l1v - mx));
        out[g*2 + 0] = l0  - lse;
        out[g*2 + 1] = l1v - lse;
    }
}

extern "C" void kernel_launch(void* const* d_in, const int* in_sizes, int n_in,
                              void* d_out, int out_size, void* d_ws, size_t ws_size,
                              hipStream_t stream) {
    const float* x      = (const float*)d_in[0];
    const int*   eidx   = (const int*)  d_in[1];
    const float* eattr  = (const float*)d_in[2];
    const float* coords = (const float*)d_in[3];
    const int*   acls   = (const int*)  d_in[4];
    const float* BkTab  = (const float*)d_in[5];
    const float* posW   = (const float*)d_in[6];
    const float* posb   = (const float*)d_in[7];
    const float* W1s    = (const float*)d_in[8];
    const float* W1n    = (const float*)d_in[9];
    const float* b1     = (const float*)d_in[10];
    const float* gn1w   = (const float*)d_in[11];
    const float* gn1b   = (const float*)d_in[12];
    const float* gn1ms  = (const float*)d_in[13];
    const float* poolp  = (const float*)d_in[14];
    const float* W2s    = (const float*)d_in[15];
    const float* W2n    = (const float*)d_in[16];
    const float* b2     = (const float*)d_in[17];
    const float* gn2w   = (const float*)d_in[18];
    const float* gn2b   = (const float*)d_in[19];
    const float* gn2ms  = (const float*)d_in[20];
    const float* l1W    = (const float*)d_in[21];
    const float* l1b    = (const float*)d_in[22];
    const float* l2W    = (const float*)d_in[23];
    const float* l2b    = (const float*)d_in[24];

    const int* row  = eidx;
    const int* colp = eidx + ET_;

    float* W = (float*)d_ws;
    const size_t NTH = (size_t)NT_ * 64;        // 2,097,152 floats
    float* b0    = W;                           // y -> y2full
    float* b1buf = W + 1*NTH;                   // hself -> hp(in-place) -> agg2
    float* b2buf = W + 2*NTH;                   // agg -> hp2
    float* b3buf = W + 3*NTH;                   // nsum / nsum2 alias -> hs2
    float* p = W + 4*NTH;
    int*   colcsr = (int*)p;         p += ET_;             // 4 MB
    int*   colptr = (int*)p;         p += NT_ + 8;
    float* deg    = p;               p += NT_;
    float* deg2   = p;               p += NP2_;
    float* tanhv  = p;               p += NP2_;
    int*   perm   = (int*)p;         p += NP2_;
    int*   nmap   = (int*)p;         p += NT_;
    int*   cls2   = (int*)p;         p += NP2_;
    float* BkT    = p;               p += 6 * 4096;
    float* PT     = p;               p += 6 * 256;
    float* meanv  = p;               p += G_ * 64;
    float* istdv  = p;               p += G_ * 64;
    float* partial= p;               p += (size_t)G_ * 8 * 128;
    float4* nsum  = (float4*)b3buf;                        // stage-1 (live nsum1s..gnprop)
    float4* nsum2 = (float4*)b3buf;                        // stage-2 (live s2pres..prop2v)

    // ---- prep ----
    k_prep     <<<102,     256,  0, stream>>>(BkTab, posW, posb, BkT, PT);
    k_buildc   <<<G_,      1024, 0, stream>>>(row, colp, colptr, colcsr, deg, nmap);

    // ---- stage 1 ----
    k_gemm_dual<<<NT_/32,  256, 0, stream>>>(x, FIN_, W1n, W1s, b1, nullptr,
                                             b0 /*y*/, b1buf /*hself*/);
    k_nsum1s   <<<G_,      1024, 0, stream>>>(row, colp, eattr, coords, nsum);
    k_gagg     <<<NT_/4,   256, 0, stream>>>(colptr, colcsr, b0 /*y*/, b2buf /*agg*/);
    k_gnstat   <<<G_*8,    256, 0, stream>>>(b1buf /*hself*/, b2buf /*agg*/, deg,
                                             partial, N_, 8, 64);
    k_gnfin    <<<G_,      64,  0, stream>>>(partial, gn1ms, 8, N_, meanv, istdv);
    k_gnprop   <<<NT_/4,   256, 0, stream>>>(b1buf /*hself*/, b2buf /*agg*/, deg,
                                             meanv, istdv, gn1w, gn1b,
                                             nsum, acls, PT, BkT,
                                             b1buf /*hp in-place*/);
    k_topk     <<<G_,      512, 0, stream>>>(b1buf /*hp*/, poolp, acls,
                                             perm, tanhv, nmap, cls2);

    // ---- stage 2 ----
    k_s2pres   <<<G_,      1024, 0, stream>>>(row, colp, nmap, coords, nsum2, deg2);
    k_prop2v   <<<NP2_/4,  256, 0, stream>>>(b1buf /*hp*/, perm, tanhv,
                                             nsum2, cls2, PT, BkT, b2buf /*hp2*/);
    hipMemsetAsync(b0, 0, NTH * sizeof(float), stream);        // y2full zero
    k_gemm_dual<<<NP2_/32, 256, 0, stream>>>(b2buf /*hp2*/, 64, W2n, W2s, b2, perm,
                                             b0 /*y2full scattered*/, b3buf /*hs2*/);
    k_gagg2    <<<NP2_/4,  256, 0, stream>>>(colptr, colcsr, perm, b0 /*y2full*/,
                                             b1buf /*agg2*/);
    k_gnstat   <<<G_*6,    256, 0, stream>>>(b3buf /*hs2*/, b1buf /*agg2*/, deg2,
                                             partial, KP_, 6, 60);
    k_gnfin    <<<G_,      64,  0, stream>>>(partial, gn2ms, 6, KP_, meanv, istdv);
    k_gnrd     <<<G_*6,    256, 0, stream>>>(b3buf /*hs2*/, b1buf /*agg2*/, deg2,
                                             meanv, istdv, gn2w, gn2b,
                                             partial, 6, 60);
    k_rfin     <<<G_,      64,  0, stream>>>(partial, 6, l1W, l1b, l2W, l2b,
                                             (float*)d_out);
}

// Round 8
// 372.018 us; speedup vs baseline: 1.2521x; 1.2521x over previous
//
#include <hip/hip_runtime.h>
#include <math.h>

#define G_    64
#define N_    512
#define H_    64
#define NT_   32768
#define ET_   1048576
#define EPG_  16384      // edges per graph
#define KP_   359
#define NP2_  22976
#define FIN_  128

// ---------------- prep: BkT transpose (blocks 0..95) + PT tables (blocks 96..101) ----
// BkT[c][d*64+h] = Bk[c][h*64+d];  PT[c][i][h] = sum_d Bk_c[h,d]*basis_i[d],
// basis 0..2 = posW rows, basis 3 = posb
__global__ void k_prep(const float* __restrict__ Bk, const float* __restrict__ posW,
                       const float* __restrict__ posb,
                       float* __restrict__ BkT, float* __restrict__ PT) {
    int b = blockIdx.x, t = threadIdx.x;
    if (b < 96) {
        int idx = b * 256 + t;
        int c = idx >> 12, r = idx & 4095;
        int h = r >> 6, d = r & 63;
        BkT[c * 4096 + d * 64 + h] = Bk[c * 4096 + h * 64 + d];
    } else {
        int c = b - 96;
        int i = t >> 6, h = t & 63;
        const float* B = Bk + c * 4096 + h * 64;
        float acc = 0.f;
        for (int d = 0; d < 64; d++) {
            float vd = (i < 3) ? posW[i*64 + d] : posb[d];
            acc += B[d] * vd;
        }
        PT[c*256 + i*64 + h] = acc;
    }
}

// ---------------- dual CSR build: hist + scan + scatter for row AND col ----------------
// One block per graph, INT LDS cursors (int LDS atomics are fast; float ones are not).
// rowcsr entry: int2(col_global, ea_bits). colcsr entry: row_global.
__global__ __launch_bounds__(1024)
void k_build2(const int* __restrict__ row, const int* __restrict__ col,
              const float* __restrict__ ea,
              int* __restrict__ rowptr, int* __restrict__ colptr,
              int2* __restrict__ rowcsr, int* __restrict__ colcsr,
              float* __restrict__ deg, int* __restrict__ nmap) {
    __shared__ int hr[N_], hc[N_];
    int g = blockIdx.x, t = threadIdx.x;
    int nbase = g * N_, ebase = g * EPG_;
    if (t < N_) { hr[t] = 0; hc[t] = 0; nmap[nbase + t] = -1; }
    __syncthreads();
    for (int i = t; i < EPG_; i += 1024) {
        atomicAdd(&hr[row[ebase + i] & (N_ - 1)], 1);
        atomicAdd(&hc[col[ebase + i] & (N_ - 1)], 1);
    }
    __syncthreads();
    if (t < N_) deg[nbase + t] = (float)hc[t];
    __syncthreads();
    int wave = t >> 6, lane = t & 63;
    if (wave < 2) {                     // wave 0 scans hr, wave 1 scans hc
        int* h = wave ? hc : hr;
        int base8 = lane * 8;
        int loc[8];
        int tot = 0;
        #pragma unroll
        for (int i = 0; i < 8; i++) { int v = h[base8 + i]; loc[i] = tot; tot += v; }
        int pref = tot;
        for (int off = 1; off < 64; off <<= 1) {
            int u = __shfl_up(pref, off);
            if (lane >= off) pref += u;
        }
        pref -= tot;                    // exclusive
        #pragma unroll
        for (int i = 0; i < 8; i++) h[base8 + i] = pref + loc[i];
    }
    __syncthreads();
    if (t < N_) {
        rowptr[nbase + t] = ebase + hr[t];
        colptr[nbase + t] = ebase + hc[t];
    }
    if (g == 0 && t == 0) { rowptr[NT_] = ET_; colptr[NT_] = ET_; }
    __syncthreads();
    for (int i = t; i < EPG_; i += 1024) {
        int rg = row[ebase + i], cg = col[ebase + i];
        float w = ea[ebase + i];
        int pr = atomicAdd(&hr[rg & (N_ - 1)], 1);
        rowcsr[ebase + pr] = make_int2(cg, __float_as_int(w));
        int pc = atomicAdd(&hc[cg & (N_ - 1)], 1);
        colcsr[ebase + pc] = rg;        // all of this graph's CSR writes from one CU
    }
}

// ---------------- stage-1 node sums (pull): nsum[n] = (Σw*cx,Σw*cy,Σw*cz,Σw) ----------
__global__ __launch_bounds__(256)
void k_nsum1(const int* __restrict__ rowptr, const int2* __restrict__ rcsr,
             const float* __restrict__ coords, float4* __restrict__ nsum) {
    int node = blockIdx.x * 4 + (threadIdx.x >> 6);
    int lane = threadIdx.x & 63;
    int start = rowptr[node], end = rowptr[node + 1];
    float sx = 0.f, sy = 0.f, sz = 0.f, sw = 0.f;
    for (int k = start + lane; k < end; k += 64) {
        int2 ent = rcsr[k];
        int c = ent.x;
        float w = __int_as_float(ent.y);
        sx += w * coords[c*3+0];
        sy += w * coords[c*3+1];
        sz += w * coords[c*3+2];
        sw += w;
    }
    #pragma unroll
    for (int off = 32; off; off >>= 1) {
        sx += __shfl_xor(sx, off); sy += __shfl_xor(sy, off);
        sz += __shfl_xor(sz, off); sw += __shfl_xor(sw, off);
    }
    if (lane == 0) nsum[node] = make_float4(sx, sy, sz, sw);
}

// ---------------- stage-2 masked node sums + deg2 (pull) ----------------
__global__ __launch_bounds__(256)
void k_s2pre(const int* __restrict__ rowptr, const int2* __restrict__ rcsr,
             const int* __restrict__ colptr, const int* __restrict__ ccsr,
             const int* __restrict__ perm, const int* __restrict__ nmap,
             const float* __restrict__ coords,
             float4* __restrict__ nsum2, float* __restrict__ deg2) {
    int j = blockIdx.x * 4 + (threadIdx.x >> 6);
    int lane = threadIdx.x & 63;
    int orig = perm[j];
    int start = rowptr[orig], end = rowptr[orig + 1];
    float sx = 0.f, sy = 0.f, sz = 0.f, sw = 0.f;
    for (int k = start + lane; k < end; k += 64) {
        int c = rcsr[k].x;
        if (nmap[c] >= 0) {
            sx += coords[c*3+0]; sy += coords[c*3+1]; sz += coords[c*3+2];
            sw += 1.f;
        }
    }
    int cs = colptr[orig], ce = colptr[orig + 1];
    float dg = 0.f;
    for (int k = cs + lane; k < ce; k += 64) {
        if (nmap[ccsr[k]] >= 0) dg += 1.f;
    }
    #pragma unroll
    for (int off = 32; off; off >>= 1) {
        sx += __shfl_xor(sx, off); sy += __shfl_xor(sy, off);
        sz += __shfl_xor(sz, off); sw += __shfl_xor(sw, off);
        dg += __shfl_xor(dg, off);
    }
    if (lane == 0) { nsum2[j] = make_float4(sx, sy, sz, sw); deg2[j] = dg; }
}

// ---------------- dual GEMM: outA = in@Wa (rows optionally scattered), outB = in@Wb + bias
__global__ __launch_bounds__(256)
void k_gemm_dual(const float* __restrict__ in, int K,
                 const float* __restrict__ Wa, const float* __restrict__ Wb,
                 const float* __restrict__ bias, const int* __restrict__ permA,
                 float* __restrict__ outA, float* __restrict__ outB) {
    __shared__ float inT[32 * FIN_];
    int row0 = blockIdx.x * 32;
    int t = threadIdx.x;
    for (int idx = t; idx < 32 * K; idx += 256) inT[idx] = in[row0 * K + idx];
    __syncthreads();
    int c = t & 63, rb = t >> 6;            // wave rb handles rows rb*8 .. rb*8+7
    const float* ip = inT + (rb * 8) * K;
    float aA[8] = {0,0,0,0,0,0,0,0};
    float aB[8] = {0,0,0,0,0,0,0,0};
    for (int k = 0; k < K; k += 4) {
        float wa0 = Wa[(k+0)*64 + c], wa1 = Wa[(k+1)*64 + c];
        float wa2 = Wa[(k+2)*64 + c], wa3 = Wa[(k+3)*64 + c];
        float wb0 = Wb[(k+0)*64 + c], wb1 = Wb[(k+1)*64 + c];
        float wb2 = Wb[(k+2)*64 + c], wb3 = Wb[(k+3)*64 + c];
        #pragma unroll
        for (int r = 0; r < 8; r++) {
            float4 xv = *(const float4*)&ip[r*K + k];
            aA[r] += xv.x*wa0; aB[r] += xv.x*wb0;
            aA[r] += xv.y*wa1; aB[r] += xv.y*wb1;
            aA[r] += xv.z*wa2; aB[r] += xv.z*wb2;
            aA[r] += xv.w*wa3; aB[r] += xv.w*wb3;
        }
    }
    float bv = bias[c];
    #pragma unroll
    for (int r = 0; r < 8; r++) {
        int node = row0 + rb*8 + r;
        int rowA = permA ? permA[node] : node;
        outA[rowA*64 + c] = aA[r];
        outB[node*64 + c] = aB[r] + bv;
    }
}

// ---------------- stage-1 agg gather ----------------
__global__ __launch_bounds__(256)
void k_gagg(const int* __restrict__ colptr, const int* __restrict__ ccsr,
            const float* __restrict__ y, float* __restrict__ agg) {
    int node = blockIdx.x * 4 + (threadIdx.x >> 6);
    int lane = threadIdx.x & 63;
    int start = colptr[node], end = colptr[node + 1];
    float acc = 0.f;
    #pragma unroll 8
    for (int k = start; k < end; k++) {
        int r = ccsr[k];
        acc += y[r*64 + lane];
    }
    agg[node*64 + lane] = acc;
}

// ---------------- graph_norm stats: one-pass sum & sumsq partials ----------------
__global__ __launch_bounds__(256)
void k_gnstat(const float* __restrict__ hs, const float* __restrict__ agg,
              const float* __restrict__ deg, float* __restrict__ partial,
              int NPG, int CH, int npc) {
    __shared__ float r1[256], r2[256];
    int b = blockIdx.x;
    int g = b / CH, chunk = b % CH;
    int t = threadIdx.x, c = t & 63, grp = t >> 6;
    int n0 = chunk * npc;
    int nend = min(n0 + npc, NPG);
    float s1 = 0.f, s2 = 0.f;
    for (int n = n0 + grp; n < nend; n += 4) {
        int node = g * NPG + n;
        float v = hs[node*64 + c] + agg[node*64 + c] / fmaxf(deg[node], 1.f);
        s1 += v; s2 += v * v;
    }
    r1[t] = s1; r2[t] = s2;
    __syncthreads();
    if (grp == 0) {
        partial[b*128 + c]      = r1[c] + r1[64+c] + r1[128+c] + r1[192+c];
        partial[b*128 + 64 + c] = r2[c] + r2[64+c] + r2[128+c] + r2[192+c];
    }
}

// ---------------- graph_norm finalize ----------------
__global__ void k_gnfin(const float* __restrict__ partial, const float* __restrict__ ms,
                        int CH, int NPG,
                        float* __restrict__ mval, float* __restrict__ istdv) {
    int g = blockIdx.x, t = threadIdx.x;   // 64 threads
    float s1 = 0.f, s2 = 0.f;
    for (int i = 0; i < CH; i++) {
        s1 += partial[(g*CH + i)*128 + t];
        s2 += partial[(g*CH + i)*128 + 64 + t];
    }
    float m = s1 / (float)NPG, q = s2 / (float)NPG, msv = ms[t];
    float var = q - msv * m * m * (2.f - msv);   // E[(h-ms*m)^2]
    mval[g*64 + t]  = msv * m;
    istdv[g*64 + t] = rsqrtf(var + 1e-5f);
}

// ---------------- stage-1 fused: gn-apply + elu + delta(from nsum) + propagate ----------------
__global__ __launch_bounds__(256)
void k_gnprop(const float* __restrict__ hself, const float* __restrict__ agg,
              const float* __restrict__ deg,
              const float* __restrict__ mval, const float* __restrict__ istdv,
              const float* __restrict__ w, const float* __restrict__ b,
              const float4* __restrict__ nsum, const int* __restrict__ cls,
              const float* __restrict__ PT, const float* __restrict__ BkT,
              float* __restrict__ out) {
    __shared__ float hT[256];
    int t = threadIdx.x;
    int node = blockIdx.x * 4 + (t >> 6);
    int lane = t & 63;
    int g = node >> 9;
    float4 s4 = nsum[node];
    int c = cls[node];
    const float* P = PT + c * 256;
    float d = s4.x*P[lane] + s4.y*P[64+lane] + s4.z*P[128+lane] + s4.w*P[192+lane];
    float v = hself[node*64 + lane] + agg[node*64 + lane] / fmaxf(deg[node], 1.f);
    v = w[lane] * (v - mval[g*64 + lane]) * istdv[g*64 + lane] + b[lane];
    v = v > 0.f ? v : expm1f(v);
    v += d;
    hT[t] = v;
    __syncthreads();
    float ssum = v;
    #pragma unroll
    for (int off = 32; off; off >>= 1) ssum += __shfl_xor(ssum, off);
    const float* B  = BkT + c * 4096;
    const float* hv = hT + (t & ~63);
    float acc = 0.f;
    #pragma unroll 8
    for (int j = 0; j < 64; j++) acc += B[j*64 + lane] * hv[j];
    out[node*64 + lane] = acc + d * ssum;
}

// ---------------- top-k per graph (desc score, ties by lower idx) ----------------
__global__ void k_topk(const float* __restrict__ hp, const float* __restrict__ p,
                       const int* __restrict__ cls,
                       int* __restrict__ perm, float* __restrict__ tanhv,
                       int* __restrict__ node_map, int* __restrict__ class2) {
    __shared__ float key[N_];
    __shared__ int   idxS[N_];
    __shared__ float pS[64];
    __shared__ float nrm;
    int g = blockIdx.x, t = threadIdx.x;
    if (t < 64) pS[t] = p[t];
    __syncthreads();
    if (t == 0) {
        float s = 0.f;
        for (int i = 0; i < 64; i++) s += pS[i] * pS[i];
        nrm = sqrtf(s);
    }
    __syncthreads();
    {
        float acc = 0.f;
        const float* hv = hp + (size_t)(g*N_ + t) * 64;
        for (int cdx = 0; cdx < 64; cdx++) acc += hv[cdx] * pS[cdx];
        key[t]  = acc / nrm;
        idxS[t] = t;
    }
    __syncthreads();
    for (int k = 2; k <= N_; k <<= 1) {
        for (int j = k >> 1; j > 0; j >>= 1) {
            int i = t, ixj = i ^ j;
            if (ixj > i) {
                float ki = key[i], kj = key[ixj];
                int   ii = idxS[i], ij = idxS[ixj];
                bool before = (ki > kj) || (ki == kj && ii < ij);
                bool dir = ((i & k) == 0);
                if (dir ? !before : before) {
                    key[i] = kj; key[ixj] = ki;
                    idxS[i] = ij; idxS[ixj] = ii;
                }
            }
            __syncthreads();
        }
    }
    if (t < KP_) {
        int orig  = idxS[t];
        int gnode = g * N_ + orig;
        int pj    = g * KP_ + t;
        perm[pj]     = gnode;
        tanhv[pj]    = tanhf(key[t]);
        node_map[gnode] = pj;
        class2[pj]   = cls[gnode];
    }
}

// ---------------- stage-2 fused: gather*tanh + delta2(from nsum2) + propagate ----------------
__global__ __launch_bounds__(256)
void k_prop2v(const float* __restrict__ hp, const int* __restrict__ perm,
              const float* __restrict__ tanhv,
              const float4* __restrict__ nsum2, const int* __restrict__ cls2,
              const float* __restrict__ PT, const float* __restrict__ BkT,
              float* __restrict__ out) {
    __shared__ float hT[256];
    int t = threadIdx.x;
    int j = blockIdx.x * 4 + (t >> 6);
    int lane = t & 63;
    int orig = perm[j];
    float tv = tanhv[j];
    float4 s4 = nsum2[j];
    int c = cls2[j];
    const float* P = PT + c * 256;
    float d = s4.x*P[lane] + s4.y*P[64+lane] + s4.z*P[128+lane] + s4.w*P[192+lane];
    float v = hp[orig*64 + lane] * tv + d;
    hT[t] = v;
    __syncthreads();
    float ssum = v;
    #pragma unroll
    for (int off = 32; off; off >>= 1) ssum += __shfl_xor(ssum, off);
    const float* B  = BkT + c * 4096;
    const float* hv = hT + (t & ~63);
    float acc = 0.f;
    #pragma unroll 8
    for (int jj = 0; jj < 64; jj++) acc += B[jj*64 + lane] * hv[jj];
    out[j*64 + lane] = acc + d * ssum;
}

// ---------------- stage-2 agg gather (zero-expanded y2full, single indirection) ----------------
__global__ __launch_bounds__(256)
void k_gagg2(const int* __restrict__ colptr, const int* __restrict__ ccsr,
             const int* __restrict__ perm, const float* __restrict__ y2full,
             float* __restrict__ agg2) {
    int j = blockIdx.x * 4 + (threadIdx.x >> 6);
    int lane = threadIdx.x & 63;
    int orig = perm[j];
    int start = colptr[orig], end = colptr[orig + 1];
    float acc = 0.f;
    #pragma unroll 8
    for (int k = start; k < end; k++) {
        int r = ccsr[k];
        acc += y2full[r*64 + lane];
    }
    agg2[j*64 + lane] = acc;
}

// ---------------- fused stage-2 gn-apply + elu + readout partials ----------------
__global__ __launch_bounds__(256)
void k_gnrd(const float* __restrict__ hs, const float* __restrict__ agg,
            const float* __restrict__ deg2,
            const float* __restrict__ mval, const float* __restrict__ istdv,
            const float* __restrict__ w, const float* __restrict__ b,
            float* __restrict__ part, int CH, int npc) {
    __shared__ float r1[256], r2[256];
    int blk = blockIdx.x;
    int g = blk / CH, chunk = blk % CH;
    int t = threadIdx.x, c = t & 63, grp = t >> 6;
    int n0 = chunk * npc, nend = min(n0 + npc, KP_);
    float mv = mval[g*64 + c], is = istdv[g*64 + c], wv = w[c], bv = b[c];
    float s = 0.f, m = -1e30f;
    for (int n = n0 + grp; n < nend; n += 4) {
        int node = g * KP_ + n;
        float v = hs[node*64 + c] + agg[node*64 + c] / fmaxf(deg2[node], 1.f);
        v = wv * (v - mv) * is + bv;
        v = v > 0.f ? v : expm1f(v);
        s += v; m = fmaxf(m, v);
    }
    r1[t] = s; r2[t] = m;
    __syncthreads();
    if (grp == 0) {
        part[blk*128 + c]      = r1[c] + r1[64+c] + r1[128+c] + r1[192+c];
        part[blk*128 + 64 + c] = fmaxf(fmaxf(r2[c], r2[64+c]), fmaxf(r2[128+c], r2[192+c]));
    }
}

// ---------------- readout finalize: lin1 relu -> lin2 -> log_softmax ----------------
__global__ void k_rfin(const float* __restrict__ part, int CH,
                       const float* __restrict__ l1W, const float* __restrict__ l1b,
                       const float* __restrict__ l2W, const float* __restrict__ l2b,
                       float* __restrict__ out) {
    __shared__ float gv[192], rS[64];
    int g = blockIdx.x, t = threadIdx.x;   // 64 threads
    float s = 0.f, m = -1e30f;
    for (int i = 0; i < CH; i++) {
        s += part[(g*CH + i)*128 + t];
        m = fmaxf(m, part[(g*CH + i)*128 + 64 + t]);
    }
    gv[t] = s / (float)KP_;
    gv[64 + t] = m;
    gv[128 + t] = s;
    __syncthreads();
    float acc = l1b[t];
    for (int k = 0; k < 192; k++) acc += gv[k] * l1W[k*64 + t];
    rS[t] = fmaxf(acc, 0.f);
    __syncthreads();
    if (t == 0) {
        float l0 = l2b[0], l1v = l2b[1];
        for (int hh = 0; hh < 64; hh++) { l0 += rS[hh]*l2W[hh*2+0]; l1v += rS[hh]*l2W[hh*2+1]; }
        float mx  = fmaxf(l0, l1v);
        float lse = mx + logf(expf(l0 - mx) + expf(l1v - mx));
        out[g*2 + 0] = l0  - lse;
        out[g*2 + 1] = l1v - lse;
    }
}

extern "C" void kernel_launch(void* const* d_in, const int* in_sizes, int n_in,
                              void* d_out, int out_size, void* d_ws, size_t ws_size,
                              hipStream_t stream) {
    const float* x      = (const float*)d_in[0];
    const int*   eidx   = (const int*)  d_in[1];
    const float* eattr  = (const float*)d_in[2];
    const float* coords = (const float*)d_in[3];
    const int*   acls   = (const int*)  d_in[4];
    const float* BkTab  = (const float*)d_in[5];
    const float* posW   = (const float*)d_in[6];
    const float* posb   = (const float*)d_in[7];
    const float* W1s    = (const float*)d_in[8];
    const float* W1n    = (const float*)d_in[9];
    const float* b1     = (const float*)d_in[10];
    const float* gn1w   = (const float*)d_in[11];
    const float* gn1b   = (const float*)d_in[12];
    const float* gn1ms  = (const float*)d_in[13];
    const float* poolp  = (const float*)d_in[14];
    const float* W2s    = (const float*)d_in[15];
    const float* W2n    = (const float*)d_in[16];
    const float* b2     = (const float*)d_in[17];
    const float* gn2w   = (const float*)d_in[18];
    const float* gn2b   = (const float*)d_in[19];
    const float* gn2ms  = (const float*)d_in[20];
    const float* l1W    = (const float*)d_in[21];
    const float* l1b    = (const float*)d_in[22];
    const float* l2W    = (const float*)d_in[23];
    const float* l2b    = (const float*)d_in[24];

    const int* row  = eidx;
    const int* colp = eidx + ET_;

    float* W = (float*)d_ws;
    const size_t NTH = (size_t)NT_ * 64;        // 2,097,152 floats
    float* b0    = W;                           // y -> y2full
    float* b1buf = W + 1*NTH;                   // hself -> hp(in-place) -> agg2
    float* b2buf = W + 2*NTH;                   // agg -> hp2
    float* b3buf = W + 3*NTH;                   // nsum / nsum2 alias -> hs2
    float* p = W + 4*NTH;
    int2*  rowcsr = (int2*)p;        p += 2*(size_t)ET_;   // 8 MB
    int*   colcsr = (int*)p;         p += ET_;             // 4 MB
    int*   rowptr = (int*)p;         p += NT_ + 8;
    int*   colptr = (int*)p;         p += NT_ + 8;
    float* deg    = p;               p += NT_;
    float* deg2   = p;               p += NP2_;
    float* tanhv  = p;               p += NP2_;
    int*   perm   = (int*)p;         p += NP2_;
    int*   nmap   = (int*)p;         p += NT_;
    int*   cls2   = (int*)p;         p += NP2_;
    float* BkT    = p;               p += 6 * 4096;
    float* PT     = p;               p += 6 * 256;
    float* meanv  = p;               p += G_ * 64;
    float* istdv  = p;               p += G_ * 64;
    float* partial= p;               p += (size_t)G_ * 8 * 128;
    float4* nsum  = (float4*)b3buf;                        // stage-1 (live nsum1..gnprop)
    float4* nsum2 = (float4*)b3buf;                        // stage-2 (live s2pre..prop2v)

    // ---- prep ----
    k_prep     <<<102,     256,  0, stream>>>(BkTab, posW, posb, BkT, PT);
    k_build2   <<<G_,      1024, 0, stream>>>(row, colp, eattr, rowptr, colptr,
                                              rowcsr, colcsr, deg, nmap);

    // ---- stage 1 ----
    k_gemm_dual<<<NT_/32,  256, 0, stream>>>(x, FIN_, W1n, W1s, b1, nullptr,
                                             b0 /*y*/, b1buf /*hself*/);
    k_nsum1    <<<NT_/4,   256, 0, stream>>>(rowptr, rowcsr, coords, nsum);
    k_gagg     <<<NT_/4,   256, 0, stream>>>(colptr, colcsr, b0 /*y*/, b2buf /*agg*/);
    k_gnstat   <<<G_*8,    256, 0, stream>>>(b1buf /*hself*/, b2buf /*agg*/, deg,
                                             partial, N_, 8, 64);
    k_gnfin    <<<G_,      64,  0, stream>>>(partial, gn1ms, 8, N_, meanv, istdv);
    k_gnprop   <<<NT_/4,   256, 0, stream>>>(b1buf /*hself*/, b2buf /*agg*/, deg,
                                             meanv, istdv, gn1w, gn1b,
                                             nsum, acls, PT, BkT,
                                             b1buf /*hp in-place*/);
    k_topk     <<<G_,      512, 0, stream>>>(b1buf /*hp*/, poolp, acls,
                                             perm, tanhv, nmap, cls2);

    // ---- stage 2 ----
    k_s2pre    <<<NP2_/4,  256, 0, stream>>>(rowptr, rowcsr, colptr, colcsr,
                                             perm, nmap, coords, nsum2, deg2);
    k_prop2v   <<<NP2_/4,  256, 0, stream>>>(b1buf /*hp*/, perm, tanhv,
                                             nsum2, cls2, PT, BkT, b2buf /*hp2*/);
    hipMemsetAsync(b0, 0, NTH * sizeof(float), stream);        // y2full zero
    k_gemm_dual<<<NP2_/32, 256, 0, stream>>>(b2buf /*hp2*/, 64, W2n, W2s, b2, perm,
                                             b0 /*y2full scattered*/, b3buf /*hs2*/);
    k_gagg2    <<<NP2_/4,  256, 0, stream>>>(colptr, colcsr, perm, b0 /*y2full*/,
                                             b1buf /*agg2*/);
    k_gnstat   <<<G_*6,    256, 0, stream>>>(b3buf /*hs2*/, b1buf /*agg2*/, deg2,
                                             partial, KP_, 6, 60);
    k_gnfin    <<<G_,      64,  0, stream>>>(partial, gn2ms, 6, KP_, meanv, istdv);
    k_gnrd     <<<G_*6,    256, 0, stream>>>(b3buf /*hs2*/, b1buf /*agg2*/, deg2,
                                             meanv, istdv, gn2w, gn2b,
                                             partial, 6, 60);
    k_rfin     <<<G_,      64,  0, stream>>>(partial, 6, l1W, l1b, l2W, l2b,
                                             (float*)d_out);
}

// Round 9
// 343.848 us; speedup vs baseline: 1.3547x; 1.0819x over previous
//
#include <hip/hip_runtime.h>
#include <math.h>

#define G_    64
#define N_    512
#define H_    64
#define NT_   32768
#define ET_   1048576
#define EPG_  16384      // edges per graph
#define KP_   359
#define NP2_  22976
#define FIN_  128
#define ESL_  2048       // edges per hist block
#define BPB_  (EPG_/ESL_)

// ---------------- prep: BkT transpose (blocks 0..95) + PT tables (blocks 96..101) ----
__global__ void k_prep(const float* __restrict__ Bk, const float* __restrict__ posW,
                       const float* __restrict__ posb,
                       float* __restrict__ BkT, float* __restrict__ PT) {
    int b = blockIdx.x, t = threadIdx.x;
    if (b < 96) {
        int idx = b * 256 + t;
        int c = idx >> 12, r = idx & 4095;
        int h = r >> 6, d = r & 63;
        BkT[c * 4096 + d * 64 + h] = Bk[c * 4096 + h * 64 + d];
    } else {
        int c = b - 96;
        int i = t >> 6, h = t & 63;
        const float* B = Bk + c * 4096 + h * 64;
        float acc = 0.f;
        for (int d = 0; d < 64; d++) {
            float vd = (i < 3) ? posW[i*64 + d] : posb[d];
            acc += B[d] * vd;
        }
        PT[c*256 + i*64 + h] = acc;
    }
}

// ---------------- build A: per-slice LDS histogram -> global hist (int atomics) -------
__global__ __launch_bounds__(256)
void k_hist(const int* __restrict__ row, const int* __restrict__ col,
            int* __restrict__ histR, int* __restrict__ histC) {
    __shared__ int hr[N_], hc[N_];
    int b = blockIdx.x, g = b >> 3, s = b & (BPB_ - 1);
    int t = threadIdx.x;
    for (int i = t; i < N_; i += 256) { hr[i] = 0; hc[i] = 0; }
    __syncthreads();
    int ebase = g * EPG_ + s * ESL_;
    for (int i = t; i < ESL_; i += 256) {
        atomicAdd(&hr[row[ebase + i] & (N_ - 1)], 1);
        atomicAdd(&hc[col[ebase + i] & (N_ - 1)], 1);
    }
    __syncthreads();
    int nbase = g * N_;
    for (int i = t; i < N_; i += 256) {
        if (hr[i]) atomicAdd(&histR[nbase + i], hr[i]);
        if (hc[i]) atomicAdd(&histC[nbase + i], hc[i]);
    }
}

// ---------------- build B: per-graph scan -> ptrs + deg + nmap init ----------------
__global__ __launch_bounds__(256)
void k_scan(const int* __restrict__ histR, const int* __restrict__ histC,
            int* __restrict__ rowptr, int* __restrict__ colptr,
            float* __restrict__ deg, int* __restrict__ nmap) {
    __shared__ int hr[N_], hc[N_];
    int g = blockIdx.x, t = threadIdx.x;
    int nbase = g * N_;
    for (int i = t; i < N_; i += 256) {
        hr[i] = histR[nbase + i];
        int c = histC[nbase + i];
        hc[i] = c;
        deg[nbase + i] = (float)c;
        nmap[nbase + i] = -1;
    }
    __syncthreads();
    int wave = t >> 6, lane = t & 63;
    if (wave < 2) {
        int* h = wave ? hc : hr;
        int base8 = lane * 8;
        int loc[8];
        int tot = 0;
        #pragma unroll
        for (int i = 0; i < 8; i++) { int v = h[base8 + i]; loc[i] = tot; tot += v; }
        int pref = tot;
        for (int off = 1; off < 64; off <<= 1) {
            int u = __shfl_up(pref, off);
            if (lane >= off) pref += u;
        }
        pref -= tot;   // exclusive
        #pragma unroll
        for (int i = 0; i < 8; i++) h[base8 + i] = pref + loc[i];
    }
    __syncthreads();
    int ebase = g * EPG_;
    for (int i = t; i < N_; i += 256) {
        rowptr[nbase + i] = ebase + hr[i];
        colptr[nbase + i] = ebase + hc[i];
    }
    if (g == 0 && t == 0) { rowptr[NT_] = ET_; colptr[NT_] = ET_; }
}

// ---------------- build C: range-owned scatter, G*4 blocks, LDS cursors ----------------
// Block (g,q) owns nodes [q*128,(q+1)*128): its rowcsr/colcsr regions are written
// only from this block -> cache lines assembled in one CU's L2 (no write-amp).
__global__ __launch_bounds__(1024)
void k_scat(const int* __restrict__ row, const int* __restrict__ col,
            const float* __restrict__ ea,
            const int* __restrict__ rowptr, const int* __restrict__ colptr,
            int2* __restrict__ rowcsr, int* __restrict__ colcsr) {
    __shared__ int curR[128], curC[128];
    int g = blockIdx.x >> 2, q = blockIdx.x & 3;
    int t = threadIdx.x;
    int lo = q * 128;
    int nbase = g * N_ + lo;
    if (t < 128) { curR[t] = rowptr[nbase + t]; curC[t] = colptr[nbase + t]; }
    __syncthreads();
    int ebase = g * EPG_;
    for (int i = t; i < EPG_; i += 1024) {
        int rg = row[ebase + i];
        int cg = col[ebase + i];
        int rl = (rg & (N_ - 1)) - lo;
        if ((unsigned)rl < 128u) {
            int pr = atomicAdd(&curR[rl], 1);
            rowcsr[pr] = make_int2(cg, __float_as_int(ea[ebase + i]));
        }
        int cl = (cg & (N_ - 1)) - lo;
        if ((unsigned)cl < 128u) {
            int pc = atomicAdd(&curC[cl], 1);
            colcsr[pc] = rg;
        }
    }
}

// ---------------- dual GEMM: outA = in@Wa (rows optionally scattered), outB = in@Wb + bias
__global__ __launch_bounds__(256)
void k_gemm_dual(const float* __restrict__ in, int K,
                 const float* __restrict__ Wa, const float* __restrict__ Wb,
                 const float* __restrict__ bias, const int* __restrict__ permA,
                 float* __restrict__ outA, float* __restrict__ outB) {
    __shared__ float inT[32 * FIN_];
    int row0 = blockIdx.x * 32;
    int t = threadIdx.x;
    for (int idx = t; idx < 32 * K; idx += 256) inT[idx] = in[row0 * K + idx];
    __syncthreads();
    int c = t & 63, rb = t >> 6;
    const float* ip = inT + (rb * 8) * K;
    float aA[8] = {0,0,0,0,0,0,0,0};
    float aB[8] = {0,0,0,0,0,0,0,0};
    for (int k = 0; k < K; k += 4) {
        float wa0 = Wa[(k+0)*64 + c], wa1 = Wa[(k+1)*64 + c];
        float wa2 = Wa[(k+2)*64 + c], wa3 = Wa[(k+3)*64 + c];
        float wb0 = Wb[(k+0)*64 + c], wb1 = Wb[(k+1)*64 + c];
        float wb2 = Wb[(k+2)*64 + c], wb3 = Wb[(k+3)*64 + c];
        #pragma unroll
        for (int r = 0; r < 8; r++) {
            float4 xv = *(const float4*)&ip[r*K + k];
            aA[r] += xv.x*wa0; aB[r] += xv.x*wb0;
            aA[r] += xv.y*wa1; aB[r] += xv.y*wb1;
            aA[r] += xv.z*wa2; aB[r] += xv.z*wb2;
            aA[r] += xv.w*wa3; aB[r] += xv.w*wb3;
        }
    }
    float bv = bias[c];
    #pragma unroll
    for (int r = 0; r < 8; r++) {
        int node = row0 + rb*8 + r;
        int rowA = permA ? permA[node] : node;
        outA[rowA*64 + c] = aA[r];
        outB[node*64 + c] = aB[r] + bv;
    }
}

// ---------------- fused stage-1 edge pulls: nsum (row CSR) + agg (col CSR) ------------
__global__ __launch_bounds__(256)
void k_edge1f(const int* __restrict__ rowptr, const int2* __restrict__ rcsr,
              const int* __restrict__ colptr, const int* __restrict__ ccsr,
              const float* __restrict__ coords, const float* __restrict__ y,
              float4* __restrict__ nsum, float* __restrict__ agg) {
    int node = blockIdx.x * 4 + (threadIdx.x >> 6);
    int lane = threadIdx.x & 63;
    // row part: nsum[node] = (Σw*cx, Σw*cy, Σw*cz, Σw)
    int rs = rowptr[node], re = rowptr[node + 1];
    float sx = 0.f, sy = 0.f, sz = 0.f, sw = 0.f;
    for (int k = rs + lane; k < re; k += 64) {
        int2 ent = rcsr[k];
        int c = ent.x;
        float w = __int_as_float(ent.y);
        sx += w * coords[c*3+0];
        sy += w * coords[c*3+1];
        sz += w * coords[c*3+2];
        sw += w;
    }
    #pragma unroll
    for (int off = 32; off; off >>= 1) {
        sx += __shfl_xor(sx, off); sy += __shfl_xor(sy, off);
        sz += __shfl_xor(sz, off); sw += __shfl_xor(sw, off);
    }
    if (lane == 0) nsum[node] = make_float4(sx, sy, sz, sw);
    // col part: agg[node,lane] = Σ y[r,lane]
    int cs = colptr[node], ce = colptr[node + 1];
    float acc = 0.f;
    #pragma unroll 8
    for (int k = cs; k < ce; k++) {
        int r = ccsr[k];
        acc += y[r*64 + lane];
    }
    agg[node*64 + lane] = acc;
}

// ---------------- graph_norm stats: one-pass sum & sumsq partials ----------------
__global__ __launch_bounds__(256)
void k_gnstat(const float* __restrict__ hs, const float* __restrict__ agg,
              const float* __restrict__ deg, float* __restrict__ partial,
              int NPG, int CH, int npc) {
    __shared__ float r1[256], r2[256];
    int b = blockIdx.x;
    int g = b / CH, chunk = b % CH;
    int t = threadIdx.x, c = t & 63, grp = t >> 6;
    int n0 = chunk * npc;
    int nend = min(n0 + npc, NPG);
    float s1 = 0.f, s2 = 0.f;
    for (int n = n0 + grp; n < nend; n += 4) {
        int node = g * NPG + n;
        float v = hs[node*64 + c] + agg[node*64 + c] / fmaxf(deg[node], 1.f);
        s1 += v; s2 += v * v;
    }
    r1[t] = s1; r2[t] = s2;
    __syncthreads();
    if (grp == 0) {
        partial[b*128 + c]      = r1[c] + r1[64+c] + r1[128+c] + r1[192+c];
        partial[b*128 + 64 + c] = r2[c] + r2[64+c] + r2[128+c] + r2[192+c];
    }
}

// ---------------- graph_norm finalize ----------------
__global__ void k_gnfin(const float* __restrict__ partial, const float* __restrict__ ms,
                        int CH, int NPG,
                        float* __restrict__ mval, float* __restrict__ istdv) {
    int g = blockIdx.x, t = threadIdx.x;   // 64 threads
    float s1 = 0.f, s2 = 0.f;
    for (int i = 0; i < CH; i++) {
        s1 += partial[(g*CH + i)*128 + t];
        s2 += partial[(g*CH + i)*128 + 64 + t];
    }
    float m = s1 / (float)NPG, q = s2 / (float)NPG, msv = ms[t];
    float var = q - msv * m * m * (2.f - msv);   // E[(h-ms*m)^2]
    mval[g*64 + t]  = msv * m;
    istdv[g*64 + t] = rsqrtf(var + 1e-5f);
}

// ---------------- stage-1 fused: gn-apply + elu + delta(from nsum) + propagate --------
__global__ __launch_bounds__(256)
void k_gnprop(const float* __restrict__ hself, const float* __restrict__ agg,
              const float* __restrict__ deg,
              const float* __restrict__ mval, const float* __restrict__ istdv,
              const float* __restrict__ w, const float* __restrict__ b,
              const float4* __restrict__ nsum, const int* __restrict__ cls,
              const float* __restrict__ PT, const float* __restrict__ BkT,
              float* __restrict__ out) {
    __shared__ float hT[256];
    int t = threadIdx.x;
    int node = blockIdx.x * 4 + (t >> 6);
    int lane = t & 63;
    int g = node >> 9;
    float4 s4 = nsum[node];
    int c = cls[node];
    const float* P = PT + c * 256;
    float d = s4.x*P[lane] + s4.y*P[64+lane] + s4.z*P[128+lane] + s4.w*P[192+lane];
    float v = hself[node*64 + lane] + agg[node*64 + lane] / fmaxf(deg[node], 1.f);
    v = w[lane] * (v - mval[g*64 + lane]) * istdv[g*64 + lane] + b[lane];
    v = v > 0.f ? v : expm1f(v);
    v += d;
    hT[t] = v;
    __syncthreads();
    float ssum = v;
    #pragma unroll
    for (int off = 32; off; off >>= 1) ssum += __shfl_xor(ssum, off);
    const float* B  = BkT + c * 4096;
    const float* hv = hT + (t & ~63);
    float acc = 0.f;
    #pragma unroll 8
    for (int j = 0; j < 64; j++) acc += B[j*64 + lane] * hv[j];
    out[node*64 + lane] = acc + d * ssum;
}

// ---------------- top-k per graph (desc score, ties by lower idx) ----------------
__global__ void k_topk(const float* __restrict__ hp, const float* __restrict__ p,
                       const int* __restrict__ cls,
                       int* __restrict__ perm, float* __restrict__ tanhv,
                       int* __restrict__ node_map, int* __restrict__ class2) {
    __shared__ float key[N_];
    __shared__ int   idxS[N_];
    __shared__ float pS[64];
    __shared__ float nrm;
    int g = blockIdx.x, t = threadIdx.x;
    if (t < 64) pS[t] = p[t];
    __syncthreads();
    if (t == 0) {
        float s = 0.f;
        for (int i = 0; i < 64; i++) s += pS[i] * pS[i];
        nrm = sqrtf(s);
    }
    __syncthreads();
    {
        float acc = 0.f;
        const float* hv = hp + (size_t)(g*N_ + t) * 64;
        for (int cdx = 0; cdx < 64; cdx++) acc += hv[cdx] * pS[cdx];
        key[t]  = acc / nrm;
        idxS[t] = t;
    }
    __syncthreads();
    for (int k = 2; k <= N_; k <<= 1) {
        for (int j = k >> 1; j > 0; j >>= 1) {
            int i = t, ixj = i ^ j;
            if (ixj > i) {
                float ki = key[i], kj = key[ixj];
                int   ii = idxS[i], ij = idxS[ixj];
                bool before = (ki > kj) || (ki == kj && ii < ij);
                bool dir = ((i & k) == 0);
                if (dir ? !before : before) {
                    key[i] = kj; key[ixj] = ki;
                    idxS[i] = ij; idxS[ixj] = ii;
                }
            }
            __syncthreads();
        }
    }
    if (t < KP_) {
        int orig  = idxS[t];
        int gnode = g * N_ + orig;
        int pj    = g * KP_ + t;
        perm[pj]     = gnode;
        tanhv[pj]    = tanhf(key[t]);
        node_map[gnode] = pj;
        class2[pj]   = cls[gnode];
    }
}

// ---------------- fused stage-2: masked sums + deg2 + gather*tanh + delta2 + propagate
__global__ __launch_bounds__(256)
void k_s2prop(const int* __restrict__ rowptr, const int2* __restrict__ rcsr,
              const int* __restrict__ colptr, const int* __restrict__ ccsr,
              const int* __restrict__ perm, const int* __restrict__ nmap,
              const float* __restrict__ coords,
              const float* __restrict__ hp, const float* __restrict__ tanhv,
              const int* __restrict__ cls2,
              const float* __restrict__ PT, const float* __restrict__ BkT,
              float* __restrict__ out, float* __restrict__ deg2) {
    __shared__ float hT[256];
    int t = threadIdx.x;
    int j = blockIdx.x * 4 + (t >> 6);
    int lane = t & 63;
    int orig = perm[j];
    int rs = rowptr[orig], re = rowptr[orig + 1];
    float sx = 0.f, sy = 0.f, sz = 0.f, sw = 0.f;
    for (int k = rs + lane; k < re; k += 64) {
        int c = rcsr[k].x;
        if (nmap[c] >= 0) {
            sx += coords[c*3+0]; sy += coords[c*3+1]; sz += coords[c*3+2];
            sw += 1.f;
        }
    }
    int cs = colptr[orig], ce = colptr[orig + 1];
    float dg = 0.f;
    for (int k = cs + lane; k < ce; k += 64) {
        if (nmap[ccsr[k]] >= 0) dg += 1.f;
    }
    #pragma unroll
    for (int off = 32; off; off >>= 1) {
        sx += __shfl_xor(sx, off); sy += __shfl_xor(sy, off);
        sz += __shfl_xor(sz, off); sw += __shfl_xor(sw, off);
        dg += __shfl_xor(dg, off);
    }
    if (lane == 0) deg2[j] = dg;
    int c = cls2[j];
    const float* P = PT + c * 256;
    float d = sx*P[lane] + sy*P[64+lane] + sz*P[128+lane] + sw*P[192+lane];
    float v = hp[orig*64 + lane] * tanhv[j] + d;
    hT[t] = v;
    __syncthreads();
    float ssum = v;
    #pragma unroll
    for (int off = 32; off; off >>= 1) ssum += __shfl_xor(ssum, off);
    const float* B  = BkT + c * 4096;
    const float* hv = hT + (t & ~63);
    float acc = 0.f;
    #pragma unroll 8
    for (int jj = 0; jj < 64; jj++) acc += B[jj*64 + lane] * hv[jj];
    out[j*64 + lane] = acc + d * ssum;
}

// ---------------- stage-2 agg gather (zero-expanded y2full, single indirection) -------
__global__ __launch_bounds__(256)
void k_gagg2(const int* __restrict__ colptr, const int* __restrict__ ccsr,
             const int* __restrict__ perm, const float* __restrict__ y2full,
             float* __restrict__ agg2) {
    int j = blockIdx.x * 4 + (threadIdx.x >> 6);
    int lane = threadIdx.x & 63;
    int orig = perm[j];
    int start = colptr[orig], end = colptr[orig + 1];
    float acc = 0.f;
    #pragma unroll 8
    for (int k = start; k < end; k++) {
        int r = ccsr[k];
        acc += y2full[r*64 + lane];
    }
    agg2[j*64 + lane] = acc;
}

// ---------------- fused stage-2 gn-apply + elu + readout partials ----------------
__global__ __launch_bounds__(256)
void k_gnrd(const float* __restrict__ hs, const float* __restrict__ agg,
            const float* __restrict__ deg2,
            const float* __restrict__ mval, const float* __restrict__ istdv,
            const float* __restrict__ w, const float* __restrict__ b,
            float* __restrict__ part, int CH, int npc) {
    __shared__ float r1[256], r2[256];
    int blk = blockIdx.x;
    int g = blk / CH, chunk = blk % CH;
    int t = threadIdx.x, c = t & 63, grp = t >> 6;
    int n0 = chunk * npc, nend = min(n0 + npc, KP_);
    float mv = mval[g*64 + c], is = istdv[g*64 + c], wv = w[c], bv = b[c];
    float s = 0.f, m = -1e30f;
    for (int n = n0 + grp; n < nend; n += 4) {
        int node = g * KP_ + n;
        float v = hs[node*64 + c] + agg[node*64 + c] / fmaxf(deg2[node], 1.f);
        v = wv * (v - mv) * is + bv;
        v = v > 0.f ? v : expm1f(v);
        s += v; m = fmaxf(m, v);
    }
    r1[t] = s; r2[t] = m;
    __syncthreads();
    if (grp == 0) {
        part[blk*128 + c]      = r1[c] + r1[64+c] + r1[128+c] + r1[192+c];
        part[blk*128 + 64 + c] = fmaxf(fmaxf(r2[c], r2[64+c]), fmaxf(r2[128+c], r2[192+c]));
    }
}

// ---------------- readout finalize: lin1 relu -> lin2 -> log_softmax ----------------
__global__ void k_rfin(const float* __restrict__ part, int CH,
                       const float* __restrict__ l1W, const float* __restrict__ l1b,
                       const float* __restrict__ l2W, const float* __restrict__ l2b,
                       float* __restrict__ out) {
    __shared__ float gv[192], rS[64];
    int g = blockIdx.x, t = threadIdx.x;   // 64 threads
    float s = 0.f, m = -1e30f;
    for (int i = 0; i < CH; i++) {
        s += part[(g*CH + i)*128 + t];
        m = fmaxf(m, part[(g*CH + i)*128 + 64 + t]);
    }
    gv[t] = s / (float)KP_;
    gv[64 + t] = m;
    gv[128 + t] = s;
    __syncthreads();
    float acc = l1b[t];
    for (int k = 0; k < 192; k++) acc += gv[k] * l1W[k*64 + t];
    rS[t] = fmaxf(acc, 0.f);
    __syncthreads();
    if (t == 0) {
        float l0 = l2b[0], l1v = l2b[1];
        for (int hh = 0; hh < 64; hh++) { l0 += rS[hh]*l2W[hh*2+0]; l1v += rS[hh]*l2W[hh*2+1]; }
        float mx  = fmaxf(l0, l1v);
        float lse = mx + logf(expf(l0 - mx) + expf(l1v - mx));
        out[g*2 + 0] = l0  - lse;
        out[g*2 + 1] = l1v - lse;
    }
}

extern "C" void kernel_launch(void* const* d_in, const int* in_sizes, int n_in,
                              void* d_out, int out_size, void* d_ws, size_t ws_size,
                              hipStream_t stream) {
    const float* x      = (const float*)d_in[0];
    const int*   eidx   = (const int*)  d_in[1];
    const float* eattr  = (const float*)d_in[2];
    const float* coords = (const float*)d_in[3];
    const int*   acls   = (const int*)  d_in[4];
    const float* BkTab  = (const float*)d_in[5];
    const float* posW   = (const float*)d_in[6];
    const float* posb   = (const float*)d_in[7];
    const float* W1s    = (const float*)d_in[8];
    const float* W1n    = (const float*)d_in[9];
    const float* b1     = (const float*)d_in[10];
    const float* gn1w   = (const float*)d_in[11];
    const float* gn1b   = (const float*)d_in[12];
    const float* gn1ms  = (const float*)d_in[13];
    const float* poolp  = (const float*)d_in[14];
    const float* W2s    = (const float*)d_in[15];
    const float* W2n    = (const float*)d_in[16];
    const float* b2     = (const float*)d_in[17];
    const float* gn2w   = (const float*)d_in[18];
    const float* gn2b   = (const float*)d_in[19];
    const float* gn2ms  = (const float*)d_in[20];
    const float* l1W    = (const float*)d_in[21];
    const float* l1b    = (const float*)d_in[22];
    const float* l2W    = (const float*)d_in[23];
    const float* l2b    = (const float*)d_in[24];

    const int* row  = eidx;
    const int* colp = eidx + ET_;

    float* W = (float*)d_ws;
    const size_t NTH = (size_t)NT_ * 64;        // 2,097,152 floats
    float* b0    = W;                           // y -> y2full
    float* b1buf = W + 1*NTH;                   // hself -> hp(in-place) -> agg2
    float* b2buf = W + 2*NTH;                   // agg -> hp2
    float* b3buf = W + 3*NTH;                   // nsum -> hs2
    float* p = W + 4*NTH;
    int2*  rowcsr = (int2*)p;        p += 2*(size_t)ET_;   // 8 MB
    int*   colcsr = (int*)p;         p += ET_;             // 4 MB
    int*   rowptr = (int*)p;         p += NT_ + 8;
    int*   colptr = (int*)p;         p += NT_ + 8;
    int*   histR  = (int*)p;         p += NT_;
    int*   histC  = (int*)p;         p += NT_;
    float* deg    = p;               p += NT_;
    float* deg2   = p;               p += NP2_;
    float* tanhv  = p;               p += NP2_;
    int*   perm   = (int*)p;         p += NP2_;
    int*   nmap   = (int*)p;         p += NT_;
    int*   cls2   = (int*)p;         p += NP2_;
    float* BkT    = p;               p += 6 * 4096;
    float* PT     = p;               p += 6 * 256;
    float* meanv  = p;               p += G_ * 64;
    float* istdv  = p;               p += G_ * 64;
    float* partial= p;               p += (size_t)G_ * 8 * 128;
    float4* nsum  = (float4*)b3buf;                        // stage-1 (live edge1f..gnprop)

    // ---- build (3-phase, parallel) ----
    hipMemsetAsync(histR, 0, 2 * NT_ * sizeof(int), stream);   // histR + histC
    k_prep     <<<102,     256,  0, stream>>>(BkTab, posW, posb, BkT, PT);
    k_hist     <<<G_*BPB_, 256,  0, stream>>>(row, colp, histR, histC);
    k_scan     <<<G_,      256,  0, stream>>>(histR, histC, rowptr, colptr, deg, nmap);
    k_scat     <<<G_*4,    1024, 0, stream>>>(row, colp, eattr, rowptr, colptr,
                                              rowcsr, colcsr);

    // ---- stage 1 ----
    k_gemm_dual<<<NT_/32,  256, 0, stream>>>(x, FIN_, W1n, W1s, b1, nullptr,
                                             b0 /*y*/, b1buf /*hself*/);
    k_edge1f   <<<NT_/4,   256, 0, stream>>>(rowptr, rowcsr, colptr, colcsr,
                                             coords, b0 /*y*/, nsum, b2buf /*agg*/);
    k_gnstat   <<<G_*8,    256, 0, stream>>>(b1buf /*hself*/, b2buf /*agg*/, deg,
                                             partial, N_, 8, 64);
    k_gnfin    <<<G_,      64,  0, stream>>>(partial, gn1ms, 8, N_, meanv, istdv);
    k_gnprop   <<<NT_/4,   256, 0, stream>>>(b1buf /*hself*/, b2buf /*agg*/, deg,
                                             meanv, istdv, gn1w, gn1b,
                                             nsum, acls, PT, BkT,
                                             b1buf /*hp in-place*/);
    k_topk     <<<G_,      512, 0, stream>>>(b1buf /*hp*/, poolp, acls,
                                             perm, tanhv, nmap, cls2);

    // ---- stage 2 ----
    k_s2prop   <<<NP2_/4,  256, 0, stream>>>(rowptr, rowcsr, colptr, colcsr,
                                             perm, nmap, coords,
                                             b1buf /*hp*/, tanhv, cls2, PT, BkT,
                                             b2buf /*hp2*/, deg2);
    hipMemsetAsync(b0, 0, NTH * sizeof(float), stream);        // y2full zero
    k_gemm_dual<<<NP2_/32, 256, 0, stream>>>(b2buf /*hp2*/, 64, W2n, W2s, b2, perm,
                                             b0 /*y2full scattered*/, b3buf /*hs2*/);
    k_gagg2    <<<NP2_/4,  256, 0, stream>>>(colptr, colcsr, perm, b0 /*y2full*/,
                                             b1buf /*agg2*/);
    k_gnstat   <<<G_*6,    256, 0, stream>>>(b3buf /*hs2*/, b1buf /*agg2*/, deg2,
                                             partial, KP_, 6, 60);
    k_gnfin    <<<G_,      64,  0, stream>>>(partial, gn2ms, 6, KP_, meanv, istdv);
    k_gnrd     <<<G_*6,    256, 0, stream>>>(b3buf /*hs2*/, b1buf /*agg2*/, deg2,
                                             meanv, istdv, gn2w, gn2b,
                                             partial, 6, 60);
    k_rfin     <<<G_,      64,  0, stream>>>(partial, 6, l1W, l1b, l2W, l2b,
                                             (float*)d_out);
}

// Round 10
// 335.214 us; speedup vs baseline: 1.3896x; 1.0258x over previous
//
#include <hip/hip_runtime.h>
#include <math.h>

#define G_    64
#define N_    512
#define H_    64
#define NT_   32768
#define ET_   1048576
#define EPG_  16384      // edges per graph
#define KP_   359
#define NP2_  22976
#define FIN_  128
#define ESL_  2048       // edges per hist block
#define BPB_  (EPG_/ESL_)

// ---------------- fused prep+hist ----------------
// blocks 0..511: per-slice histograms (non-atomic global write, slice-owned region)
// blocks 512..607: BkT transpose;  blocks 608..613: PT tables
__global__ __launch_bounds__(256)
void k_histprep(const int* __restrict__ row, const int* __restrict__ col,
                int* __restrict__ histR8, int* __restrict__ histC8,
                const float* __restrict__ Bk, const float* __restrict__ posW,
                const float* __restrict__ posb,
                float* __restrict__ BkT, float* __restrict__ PT) {
    int b = blockIdx.x, t = threadIdx.x;
    if (b < G_ * BPB_) {
        __shared__ int hr[N_], hc[N_];
        int g = b >> 3, s = b & (BPB_ - 1);
        for (int i = t; i < N_; i += 256) { hr[i] = 0; hc[i] = 0; }
        __syncthreads();
        int ebase = g * EPG_ + s * ESL_;
        for (int i = t; i < ESL_; i += 256) {
            atomicAdd(&hr[row[ebase + i] & (N_ - 1)], 1);
            atomicAdd(&hc[col[ebase + i] & (N_ - 1)], 1);
        }
        __syncthreads();
        int sbase = (g * BPB_ + s) * N_;
        for (int i = t; i < N_; i += 256) {
            histR8[sbase + i] = hr[i];
            histC8[sbase + i] = hc[i];
        }
    } else if (b < G_ * BPB_ + 96) {
        int idx = (b - G_ * BPB_) * 256 + t;
        int c = idx >> 12, r = idx & 4095;
        int h = r >> 6, d = r & 63;
        BkT[c * 4096 + d * 64 + h] = Bk[c * 4096 + h * 64 + d];
    } else {
        int c = b - (G_ * BPB_ + 96);
        int i = t >> 6, h = t & 63;
        const float* B = Bk + c * 4096 + h * 64;
        float acc = 0.f;
        for (int d = 0; d < 64; d++) {
            float vd = (i < 3) ? posW[i*64 + d] : posb[d];
            acc += B[d] * vd;
        }
        PT[c*256 + i*64 + h] = acc;
    }
}

// ---------------- build B: per-graph scan (sums 8 slices) -> ptrs + deg + nmap --------
__global__ __launch_bounds__(256)
void k_scan(const int* __restrict__ histR8, const int* __restrict__ histC8,
            int* __restrict__ rowptr, int* __restrict__ colptr,
            float* __restrict__ deg, int* __restrict__ nmap) {
    __shared__ int hr[N_], hc[N_];
    int g = blockIdx.x, t = threadIdx.x;
    int nbase = g * N_;
    for (int i = t; i < N_; i += 256) {
        int sr = 0, sc = 0;
        #pragma unroll
        for (int s = 0; s < BPB_; s++) {
            sr += histR8[(g * BPB_ + s) * N_ + i];
            sc += histC8[(g * BPB_ + s) * N_ + i];
        }
        hr[i] = sr; hc[i] = sc;
        deg[nbase + i] = (float)sc;
        nmap[nbase + i] = -1;
    }
    __syncthreads();
    int wave = t >> 6, lane = t & 63;
    if (wave < 2) {
        int* h = wave ? hc : hr;
        int base8 = lane * 8;
        int loc[8];
        int tot = 0;
        #pragma unroll
        for (int i = 0; i < 8; i++) { int v = h[base8 + i]; loc[i] = tot; tot += v; }
        int pref = tot;
        for (int off = 1; off < 64; off <<= 1) {
            int u = __shfl_up(pref, off);
            if (lane >= off) pref += u;
        }
        pref -= tot;   // exclusive
        #pragma unroll
        for (int i = 0; i < 8; i++) h[base8 + i] = pref + loc[i];
    }
    __syncthreads();
    int ebase = g * EPG_;
    for (int i = t; i < N_; i += 256) {
        rowptr[nbase + i] = ebase + hr[i];
        colptr[nbase + i] = ebase + hc[i];
    }
    if (g == 0 && t == 0) { rowptr[NT_] = ET_; colptr[NT_] = ET_; }
}

// ---------------- build C: range-owned scatter, G*4 blocks, LDS cursors ---------------
__global__ __launch_bounds__(1024)
void k_scat(const int* __restrict__ row, const int* __restrict__ col,
            const float* __restrict__ ea,
            const int* __restrict__ rowptr, const int* __restrict__ colptr,
            int2* __restrict__ rowcsr, int* __restrict__ colcsr) {
    __shared__ int curR[128], curC[128];
    int g = blockIdx.x >> 2, q = blockIdx.x & 3;
    int t = threadIdx.x;
    int lo = q * 128;
    int nbase = g * N_ + lo;
    if (t < 128) { curR[t] = rowptr[nbase + t]; curC[t] = colptr[nbase + t]; }
    __syncthreads();
    int ebase = g * EPG_;
    for (int i = t; i < EPG_; i += 1024) {
        int rg = row[ebase + i];
        int cg = col[ebase + i];
        int rl = (rg & (N_ - 1)) - lo;
        if ((unsigned)rl < 128u) {
            int pr = atomicAdd(&curR[rl], 1);
            rowcsr[pr] = make_int2(cg, __float_as_int(ea[ebase + i]));
        }
        int cl = (cg & (N_ - 1)) - lo;
        if ((unsigned)cl < 128u) {
            int pc = atomicAdd(&curC[cl], 1);
            colcsr[pc] = rg;
        }
    }
}

// ---------------- dual GEMM: outA = in@Wa, outB = in@Wb + bias ----------------
__global__ __launch_bounds__(256)
void k_gemm_dual(const float* __restrict__ in, int K,
                 const float* __restrict__ Wa, const float* __restrict__ Wb,
                 const float* __restrict__ bias,
                 float* __restrict__ outA, float* __restrict__ outB) {
    __shared__ float inT[32 * FIN_];
    int row0 = blockIdx.x * 32;
    int t = threadIdx.x;
    for (int idx = t; idx < 32 * K; idx += 256) inT[idx] = in[row0 * K + idx];
    __syncthreads();
    int c = t & 63, rb = t >> 6;
    const float* ip = inT + (rb * 8) * K;
    float aA[8] = {0,0,0,0,0,0,0,0};
    float aB[8] = {0,0,0,0,0,0,0,0};
    for (int k = 0; k < K; k += 4) {
        float wa0 = Wa[(k+0)*64 + c], wa1 = Wa[(k+1)*64 + c];
        float wa2 = Wa[(k+2)*64 + c], wa3 = Wa[(k+3)*64 + c];
        float wb0 = Wb[(k+0)*64 + c], wb1 = Wb[(k+1)*64 + c];
        float wb2 = Wb[(k+2)*64 + c], wb3 = Wb[(k+3)*64 + c];
        #pragma unroll
        for (int r = 0; r < 8; r++) {
            float4 xv = *(const float4*)&ip[r*K + k];
            aA[r] += xv.x*wa0; aB[r] += xv.x*wb0;
            aA[r] += xv.y*wa1; aB[r] += xv.y*wb1;
            aA[r] += xv.z*wa2; aB[r] += xv.z*wb2;
            aA[r] += xv.w*wa3; aB[r] += xv.w*wb3;
        }
    }
    float bv = bias[c];
    #pragma unroll
    for (int r = 0; r < 8; r++) {
        int node = row0 + rb*8 + r;
        outA[node*64 + c] = aA[r];
        outB[node*64 + c] = aB[r] + bv;
    }
}

// ---------------- fused stage-1 edge pulls: nsum (row CSR) + agg (col CSR) ------------
__global__ __launch_bounds__(256)
void k_edge1f(const int* __restrict__ rowptr, const int2* __restrict__ rcsr,
              const int* __restrict__ colptr, const int* __restrict__ ccsr,
              const float* __restrict__ coords, const float* __restrict__ y,
              float4* __restrict__ nsum, float* __restrict__ agg) {
    int node = blockIdx.x * 4 + (threadIdx.x >> 6);
    int lane = threadIdx.x & 63;
    int rs = rowptr[node], re = rowptr[node + 1];
    float sx = 0.f, sy = 0.f, sz = 0.f, sw = 0.f;
    for (int k = rs + lane; k < re; k += 64) {
        int2 ent = rcsr[k];
        int c = ent.x;
        float w = __int_as_float(ent.y);
        sx += w * coords[c*3+0];
        sy += w * coords[c*3+1];
        sz += w * coords[c*3+2];
        sw += w;
    }
    #pragma unroll
    for (int off = 32; off; off >>= 1) {
        sx += __shfl_xor(sx, off); sy += __shfl_xor(sy, off);
        sz += __shfl_xor(sz, off); sw += __shfl_xor(sw, off);
    }
    if (lane == 0) nsum[node] = make_float4(sx, sy, sz, sw);
    int cs = colptr[node], ce = colptr[node + 1];
    float acc = 0.f;
    #pragma unroll 8
    for (int k = cs; k < ce; k++) {
        int r = ccsr[k];
        acc += y[r*64 + lane];
    }
    agg[node*64 + lane] = acc;
}

// ---------------- graph_norm stats: one-pass sum & sumsq partials ----------------
__global__ __launch_bounds__(256)
void k_gnstat(const float* __restrict__ hs, const float* __restrict__ agg,
              const float* __restrict__ deg, float* __restrict__ partial,
              int NPG, int CH, int npc) {
    __shared__ float r1[256], r2[256];
    int b = blockIdx.x;
    int g = b / CH, chunk = b % CH;
    int t = threadIdx.x, c = t & 63, grp = t >> 6;
    int n0 = chunk * npc;
    int nend = min(n0 + npc, NPG);
    float s1 = 0.f, s2 = 0.f;
    for (int n = n0 + grp; n < nend; n += 4) {
        int node = g * NPG + n;
        float v = hs[node*64 + c] + agg[node*64 + c] / fmaxf(deg[node], 1.f);
        s1 += v; s2 += v * v;
    }
    r1[t] = s1; r2[t] = s2;
    __syncthreads();
    if (grp == 0) {
        partial[b*128 + c]      = r1[c] + r1[64+c] + r1[128+c] + r1[192+c];
        partial[b*128 + 64 + c] = r2[c] + r2[64+c] + r2[128+c] + r2[192+c];
    }
}

// ---------------- stage-1 fused: gn-finalize + apply + elu + delta + propagate --------
__global__ __launch_bounds__(256)
void k_gnprop(const float* __restrict__ hself, const float* __restrict__ agg,
              const float* __restrict__ deg, const float* __restrict__ partial,
              const float* __restrict__ ms,
              const float* __restrict__ w, const float* __restrict__ b,
              const float4* __restrict__ nsum, const int* __restrict__ cls,
              const float* __restrict__ PT, const float* __restrict__ BkT,
              float* __restrict__ out) {
    __shared__ float hT[256];
    int t = threadIdx.x;
    int node = blockIdx.x * 4 + (t >> 6);
    int lane = t & 63;
    int g = (blockIdx.x * 4) >> 9;
    // inline graph_norm finalize for this graph/channel
    float s1 = 0.f, s2 = 0.f;
    #pragma unroll
    for (int i = 0; i < 8; i++) {
        s1 += partial[(g*8 + i)*128 + lane];
        s2 += partial[(g*8 + i)*128 + 64 + lane];
    }
    float m  = s1 / (float)N_, q = s2 / (float)N_, msv = ms[lane];
    float var = q - msv * m * m * (2.f - msv);
    float mval = msv * m;
    float istd = rsqrtf(var + 1e-5f);
    float4 s4 = nsum[node];
    int c = cls[node];
    const float* P = PT + c * 256;
    float d = s4.x*P[lane] + s4.y*P[64+lane] + s4.z*P[128+lane] + s4.w*P[192+lane];
    float v = hself[node*64 + lane] + agg[node*64 + lane] / fmaxf(deg[node], 1.f);
    v = w[lane] * (v - mval) * istd + b[lane];
    v = v > 0.f ? v : expm1f(v);
    v += d;
    hT[t] = v;
    __syncthreads();
    float ssum = v;
    #pragma unroll
    for (int off = 32; off; off >>= 1) ssum += __shfl_xor(ssum, off);
    const float* B  = BkT + c * 4096;
    const float* hv = hT + (t & ~63);
    float acc = 0.f;
    #pragma unroll 8
    for (int j = 0; j < 64; j++) acc += B[j*64 + lane] * hv[j];
    out[node*64 + lane] = acc + d * ssum;
}

// ---------------- top-k per graph + ccsr2 remap ----------------
__global__ __launch_bounds__(512)
void k_topk(const float* __restrict__ hp, const float* __restrict__ p,
            const int* __restrict__ cls, const int* __restrict__ ccsr,
            int* __restrict__ perm, float* __restrict__ tanhv,
            int* __restrict__ node_map, int* __restrict__ class2,
            int* __restrict__ ccsr2) {
    __shared__ float key[N_];
    __shared__ int   idxS[N_];
    __shared__ int   lmap[N_];
    __shared__ float pS[64];
    __shared__ float nrm;
    int g = blockIdx.x, t = threadIdx.x;
    lmap[t] = -1;
    if (t < 64) pS[t] = p[t];
    __syncthreads();
    if (t == 0) {
        float s = 0.f;
        for (int i = 0; i < 64; i++) s += pS[i] * pS[i];
        nrm = sqrtf(s);
    }
    __syncthreads();
    {
        float acc = 0.f;
        const float* hv = hp + (size_t)(g*N_ + t) * 64;
        for (int cdx = 0; cdx < 64; cdx++) acc += hv[cdx] * pS[cdx];
        key[t]  = acc / nrm;
        idxS[t] = t;
    }
    __syncthreads();
    for (int k = 2; k <= N_; k <<= 1) {
        for (int j = k >> 1; j > 0; j >>= 1) {
            int i = t, ixj = i ^ j;
            if (ixj > i) {
                float ki = key[i], kj = key[ixj];
                int   ii = idxS[i], ij = idxS[ixj];
                bool before = (ki > kj) || (ki == kj && ii < ij);
                bool dir = ((i & k) == 0);
                if (dir ? !before : before) {
                    key[i] = kj; key[ixj] = ki;
                    idxS[i] = ij; idxS[ixj] = ii;
                }
            }
            __syncthreads();
        }
    }
    if (t < KP_) {
        int orig  = idxS[t];
        int gnode = g * N_ + orig;
        int pj    = g * KP_ + t;
        perm[pj]     = gnode;
        tanhv[pj]    = tanhf(key[t]);
        node_map[gnode] = pj;
        class2[pj]   = cls[gnode];
        lmap[orig]   = pj;
    }
    __syncthreads();
    // remap this graph's colcsr to pooled row ids (invalid -> zero row NP2_)
    int ebase = g * EPG_;
    for (int k = t; k < EPG_; k += 512) {
        int mm = lmap[ccsr[ebase + k] & (N_ - 1)];
        ccsr2[ebase + k] = (mm >= 0) ? mm : NP2_;
    }
}

// ---------------- fused stage-2: masked sums + deg2 + gather*tanh + delta2 + propagate
__global__ __launch_bounds__(256)
void k_s2prop(const int* __restrict__ rowptr, const int2* __restrict__ rcsr,
              const int* __restrict__ colptr, const int* __restrict__ ccsr,
              const int* __restrict__ perm, const int* __restrict__ nmap,
              const float* __restrict__ coords,
              const float* __restrict__ hp, const float* __restrict__ tanhv,
              const int* __restrict__ cls2,
              const float* __restrict__ PT, const float* __restrict__ BkT,
              float* __restrict__ out, float* __restrict__ deg2,
              float* __restrict__ y2zero) {
    __shared__ float hT[256];
    int t = threadIdx.x;
    int j = blockIdx.x * 4 + (t >> 6);
    int lane = t & 63;
    if (blockIdx.x == 0 && t < 64) y2zero[t] = 0.f;   // zero row NP2_ for gagg2
    int orig = perm[j];
    int rs = rowptr[orig], re = rowptr[orig + 1];
    float sx = 0.f, sy = 0.f, sz = 0.f, sw = 0.f;
    for (int k = rs + lane; k < re; k += 64) {
        int c = rcsr[k].x;
        if (nmap[c] >= 0) {
            sx += coords[c*3+0]; sy += coords[c*3+1]; sz += coords[c*3+2];
            sw += 1.f;
        }
    }
    int cs = colptr[orig], ce = colptr[orig + 1];
    float dg = 0.f;
    for (int k = cs + lane; k < ce; k += 64) {
        if (nmap[ccsr[k]] >= 0) dg += 1.f;
    }
    #pragma unroll
    for (int off = 32; off; off >>= 1) {
        sx += __shfl_xor(sx, off); sy += __shfl_xor(sy, off);
        sz += __shfl_xor(sz, off); sw += __shfl_xor(sw, off);
        dg += __shfl_xor(dg, off);
    }
    if (lane == 0) deg2[j] = dg;
    int c = cls2[j];
    const float* P = PT + c * 256;
    float d = sx*P[lane] + sy*P[64+lane] + sz*P[128+lane] + sw*P[192+lane];
    float v = hp[orig*64 + lane] * tanhv[j] + d;
    hT[t] = v;
    __syncthreads();
    float ssum = v;
    #pragma unroll
    for (int off = 32; off; off >>= 1) ssum += __shfl_xor(ssum, off);
    const float* B  = BkT + c * 4096;
    const float* hv = hT + (t & ~63);
    float acc = 0.f;
    #pragma unroll 8
    for (int jj = 0; jj < 64; jj++) acc += B[jj*64 + lane] * hv[jj];
    out[j*64 + lane] = acc + d * ssum;
}

// ---------------- stage-2 agg gather via remapped ccsr2 (compact y2 + zero row) -------
__global__ __launch_bounds__(256)
void k_gagg2(const int* __restrict__ colptr, const int* __restrict__ ccsr2,
             const int* __restrict__ perm, const float* __restrict__ y2,
             float* __restrict__ agg2) {
    int j = blockIdx.x * 4 + (threadIdx.x >> 6);
    int lane = threadIdx.x & 63;
    int orig = perm[j];
    int start = colptr[orig], end = colptr[orig + 1];
    float acc = 0.f;
    #pragma unroll 8
    for (int k = start; k < end; k++) {
        int r = ccsr2[k];
        acc += y2[r*64 + lane];
    }
    agg2[j*64 + lane] = acc;
}

// ---------------- fused stage-2 gn-finalize + apply + elu + readout partials ----------
__global__ __launch_bounds__(256)
void k_gnrd(const float* __restrict__ hs, const float* __restrict__ agg,
            const float* __restrict__ deg2, const float* __restrict__ statsP,
            const float* __restrict__ ms,
            const float* __restrict__ w, const float* __restrict__ b,
            float* __restrict__ readP) {
    __shared__ float r1[256], r2[256];
    int blk = blockIdx.x;
    int g = blk / 6, chunk = blk % 6;
    int t = threadIdx.x, c = t & 63, grp = t >> 6;
    // inline finalize
    float s1 = 0.f, s2 = 0.f;
    #pragma unroll
    for (int i = 0; i < 6; i++) {
        s1 += statsP[(g*6 + i)*128 + c];
        s2 += statsP[(g*6 + i)*128 + 64 + c];
    }
    float mean = s1 / (float)KP_, q = s2 / (float)KP_, msv = ms[c];
    float var = q - msv * mean * mean * (2.f - msv);
    float mv = msv * mean;
    float is = rsqrtf(var + 1e-5f);
    float wv = w[c], bv = b[c];
    int n0 = chunk * 60, nend = min(n0 + 60, KP_);
    float s = 0.f, m = -1e30f;
    for (int n = n0 + grp; n < nend; n += 4) {
        int node = g * KP_ + n;
        float v = hs[node*64 + c] + agg[node*64 + c] / fmaxf(deg2[node], 1.f);
        v = wv * (v - mv) * is + bv;
        v = v > 0.f ? v : expm1f(v);
        s += v; m = fmaxf(m, v);
    }
    r1[t] = s; r2[t] = m;
    __syncthreads();
    if (grp == 0) {
        readP[blk*128 + c]      = r1[c] + r1[64+c] + r1[128+c] + r1[192+c];
        readP[blk*128 + 64 + c] = fmaxf(fmaxf(r2[c], r2[64+c]), fmaxf(r2[128+c], r2[192+c]));
    }
}

// ---------------- readout finalize: lin1 relu -> lin2 -> log_softmax ----------------
__global__ void k_rfin(const float* __restrict__ part, int CH,
                       const float* __restrict__ l1W, const float* __restrict__ l1b,
                       const float* __restrict__ l2W, const float* __restrict__ l2b,
                       float* __restrict__ out) {
    __shared__ float gv[192], rS[64];
    int g = blockIdx.x, t = threadIdx.x;   // 64 threads
    float s = 0.f, m = -1e30f;
    for (int i = 0; i < CH; i++) {
        s += part[(g*CH + i)*128 + t];
        m = fmaxf(m, part[(g*CH + i)*128 + 64 + t]);
    }
    gv[t] = s / (float)KP_;
    gv[64 + t] = m;
    gv[128 + t] = s;
    __syncthreads();
    float acc = l1b[t];
    for (int k = 0; k < 192; k++) acc += gv[k] * l1W[k*64 + t];
    rS[t] = fmaxf(acc, 0.f);
    __syncthreads();
    if (t == 0) {
        float l0 = l2b[0], l1v = l2b[1];
        for (int hh = 0; hh < 64; hh++) { l0 += rS[hh]*l2W[hh*2+0]; l1v += rS[hh]*l2W[hh*2+1]; }
        float mx  = fmaxf(l0, l1v);
        float lse = mx + logf(expf(l0 - mx) + expf(l1v - mx));
        out[g*2 + 0] = l0  - lse;
        out[g*2 + 1] = l1v - lse;
    }
}

extern "C" void kernel_launch(void* const* d_in, const int* in_sizes, int n_in,
                              void* d_out, int out_size, void* d_ws, size_t ws_size,
                              hipStream_t stream) {
    const float* x      = (const float*)d_in[0];
    const int*   eidx   = (const int*)  d_in[1];
    const float* eattr  = (const float*)d_in[2];
    const float* coords = (const float*)d_in[3];
    const int*   acls   = (const int*)  d_in[4];
    const float* BkTab  = (const float*)d_in[5];
    const float* posW   = (const float*)d_in[6];
    const float* posb   = (const float*)d_in[7];
    const float* W1s    = (const float*)d_in[8];
    const float* W1n    = (const float*)d_in[9];
    const float* b1     = (const float*)d_in[10];
    const float* gn1w   = (const float*)d_in[11];
    const float* gn1b   = (const float*)d_in[12];
    const float* gn1ms  = (const float*)d_in[13];
    const float* poolp  = (const float*)d_in[14];
    const float* W2s    = (const float*)d_in[15];
    const float* W2n    = (const float*)d_in[16];
    const float* b2     = (const float*)d_in[17];
    const float* gn2w   = (const float*)d_in[18];
    const float* gn2b   = (const float*)d_in[19];
    const float* gn2ms  = (const float*)d_in[20];
    const float* l1W    = (const float*)d_in[21];
    const float* l1b    = (const float*)d_in[22];
    const float* l2W    = (const float*)d_in[23];
    const float* l2b    = (const float*)d_in[24];

    const int* row  = eidx;
    const int* colp = eidx + ET_;

    float* W = (float*)d_ws;
    const size_t NTH = (size_t)NT_ * 64;        // 2,097,152 floats
    float* b0    = W;                           // y -> y2 (compact, + zero row NP2_)
    float* b1buf = W + 1*NTH;                   // hself -> hp(in-place) -> agg2
    float* b2buf = W + 2*NTH;                   // agg -> hp2
    float* b3buf = W + 3*NTH;                   // nsum -> hs2
    float* p = W + 4*NTH;
    int2*  rowcsr = (int2*)p;        p += 2*(size_t)ET_;   // 8 MB
    int*   colcsr = (int*)p;         p += ET_;             // 4 MB
    int*   ccsr2  = (int*)p;         p += ET_;             // 4 MB
    int*   rowptr = (int*)p;         p += NT_ + 8;
    int*   colptr = (int*)p;         p += NT_ + 8;
    int*   histR8 = (int*)p;         p += NT_ * BPB_ / 1;  // G*8*N = 256K ints
    int*   histC8 = (int*)p;         p += NT_ * BPB_ / 1;
    float* deg    = p;               p += NT_;
    float* deg2   = p;               p += NP2_;
    float* tanhv  = p;               p += NP2_;
    int*   perm   = (int*)p;         p += NP2_;
    int*   nmap   = (int*)p;         p += NT_;
    int*   cls2   = (int*)p;         p += NP2_;
    float* BkT    = p;               p += 6 * 4096;
    float* PT     = p;               p += 6 * 256;
    float* statsP = p;               p += (size_t)G_ * 8 * 128;
    float* readP  = p;               p += (size_t)G_ * 6 * 128;
    float4* nsum  = (float4*)b3buf;                        // stage-1 (live edge1f..gnprop)

    // ---- build ----
    k_histprep <<<G_*BPB_ + 102, 256, 0, stream>>>(row, colp, histR8, histC8,
                                                   BkTab, posW, posb, BkT, PT);
    k_scan     <<<G_,      256,  0, stream>>>(histR8, histC8, rowptr, colptr, deg, nmap);
    k_scat     <<<G_*4,    1024, 0, stream>>>(row, colp, eattr, rowptr, colptr,
                                              rowcsr, colcsr);

    // ---- stage 1 ----
    k_gemm_dual<<<NT_/32,  256, 0, stream>>>(x, FIN_, W1n, W1s, b1,
                                             b0 /*y*/, b1buf /*hself*/);
    k_edge1f   <<<NT_/4,   256, 0, stream>>>(rowptr, rowcsr, colptr, colcsr,
                                             coords, b0 /*y*/, nsum, b2buf /*agg*/);
    k_gnstat   <<<G_*8,    256, 0, stream>>>(b1buf /*hself*/, b2buf /*agg*/, deg,
                                             statsP, N_, 8, 64);
    k_gnprop   <<<NT_/4,   256, 0, stream>>>(b1buf /*hself*/, b2buf /*agg*/, deg,
                                             statsP, gn1ms, gn1w, gn1b,
                                             nsum, acls, PT, BkT,
                                             b1buf /*hp in-place*/);
    k_topk     <<<G_,      512, 0, stream>>>(b1buf /*hp*/, poolp, acls, colcsr,
                                             perm, tanhv, nmap, cls2, ccsr2);

    // ---- stage 2 ----
    k_s2prop   <<<NP2_/4,  256, 0, stream>>>(rowptr, rowcsr, colptr, colcsr,
                                             perm, nmap, coords,
                                             b1buf /*hp*/, tanhv, cls2, PT, BkT,
                                             b2buf /*hp2*/, deg2,
                                             b0 + (size_t)NP2_ * 64 /*zero row*/);
    k_gemm_dual<<<NP2_/32, 256, 0, stream>>>(b2buf /*hp2*/, 64, W2n, W2s, b2,
                                             b0 /*y2 compact*/, b3buf /*hs2*/);
    k_gagg2    <<<NP2_/4,  256, 0, stream>>>(colptr, ccsr2, perm, b0 /*y2*/,
                                             b1buf /*agg2*/);
    k_gnstat   <<<G_*6,    256, 0, stream>>>(b3buf /*hs2*/, b1buf /*agg2*/, deg2,
                                             statsP, KP_, 6, 60);
    k_gnrd     <<<G_*6,    256, 0, stream>>>(b3buf /*hs2*/, b1buf /*agg2*/, deg2,
                                             statsP, gn2ms, gn2w, gn2b, readP);
    k_rfin     <<<G_,      64,  0, stream>>>(readP, 6, l1W, l1b, l2W, l2b,
                                             (float*)d_out);
}